// Round 9
// baseline (326.423 us; speedup 1.0000x reference)
//
#include <hip/hip_runtime.h>
#include <math.h>

#define NN 384
#define DD 128
#define HH 128

__device__ __forceinline__ float sigmoidf_(float x) { return 1.f / (1.f + __expf(-x)); }
__device__ __forceinline__ float tanhf_(float x)    { return 1.f - 2.f / (__expf(2.f * x) + 1.f); }

// ================= k_start: 768 blocks x 256 thr, 2 rows/block ============
// Blocks 0..383: ligand embed + h/hA(layer0). Blocks 384..767: protein embed
// + pair projection (p2q packed). 12 waves/CU.
__global__ __launch_bounds__(256) void k_start(
    const float* __restrict__ h1, const float* __restrict__ h2,
    const float* __restrict__ nW,
    const float* __restrict__ W, const float* __restrict__ Wb, const float* __restrict__ A,
    const float* __restrict__ pW1,
    const float* __restrict__ delta_uff, const float* __restrict__ duff,
    float* __restrict__ h1g, float* __restrict__ h2g,
    float* __restrict__ hb, float* __restrict__ hAb,
    float* __restrict__ hT, float* __restrict__ hAT,
    float* __restrict__ p2q, float* __restrict__ out) {
  int blk = blockIdx.x, tid = threadIdx.x, c = tid & 127, g = tid >> 7;  // g in {0,1}
  if (blk == 0 && tid < 8) {
    int bb = tid >> 2, cc = tid & 3;
    out[tid] = (cc == 2) ? duff[0] * duff[0] * delta_uff[bb] : 0.f;
  }
  if (blk < 384) {
    int r = blk * 2 + g;
    // embed
    const float* xr = h1 + r * 54;
    float acc = 0.f;
#pragma unroll 6
    for (int k = 0; k < 54; ++k) acc += xr[k] * nW[k * DD + c];
    h1g[r * DD + c] = acc;
    __syncthreads();
    // h = x@W + Wb (x row via wave-uniform float4)
    const float4* xr4 = (const float4*)(h1g + r * DD);
    float a0 = 0.f, a1 = 0.f;
#pragma unroll 4
    for (int k4 = 0; k4 < DD / 4; ++k4) {
      float4 xv = xr4[k4]; int k = 4 * k4;
      a0 += xv.x * W[k * DD + c] + xv.z * W[(k + 2) * DD + c];
      a1 += xv.y * W[(k + 1) * DD + c] + xv.w * W[(k + 3) * DD + c];
    }
    float hv = a0 + a1 + Wb[c];
    hb[r * DD + c] = hv; hT[c * 768 + r] = hv;
    __syncthreads();
    // hA = h@A
    const float4* hr4 = (const float4*)(hb + r * DD);
    a0 = 0.f; a1 = 0.f;
#pragma unroll 4
    for (int k4 = 0; k4 < DD / 4; ++k4) {
      float4 xv = hr4[k4]; int k = 4 * k4;
      a0 += xv.x * A[k * DD + c] + xv.z * A[(k + 2) * DD + c];
      a1 += xv.y * A[(k + 1) * DD + c] + xv.w * A[(k + 3) * DD + c];
    }
    float av = a0 + a1;
    hAb[r * DD + c] = av; hAT[c * 768 + r] = av;
  } else {
    int r0 = (blk - 384) * 2;
    int r = r0 + g;
    const float* xr = h2 + r * 54;
    float acc = 0.f;
#pragma unroll 6
    for (int k = 0; k < 54; ++k) acc += xr[k] * nW[k * DD + c];
    h2g[r * DD + c] = acc;
    __syncthreads();
    const float* xbase = h2g + r0 * DD;  // block-uniform -> scalar path
    for (int o = tid; o < 640; o += 256) {
      int m = o >> 7, hc = o & 127;
      const float* Wcol = pW1 + (m * 256 + 128) * HH + hc;
      float a0 = 0.f, a1 = 0.f;
#pragma unroll 4
      for (int k = 0; k < DD; ++k) {
        float w = Wcol[k * HH];
        a0 += xbase[k] * w;
        a1 += xbase[DD + k] * w;
      }
      float* dst = p2q + (size_t)((m * 32 + (hc >> 2)) * 768 + r0) * 4 + (hc & 3);
      dst[0] = a0; dst[4] = a1;
    }
  }
}

// ================= k_att: 768 blocks x 384 thr, 1 column/block =============
__global__ __launch_bounds__(384) void k_att(
    const float* __restrict__ hb, const float* __restrict__ hAb,
    const float* __restrict__ hT, const float* __restrict__ hAT,
    const float* __restrict__ adj, float* __restrict__ att) {
  int col = blockIdx.x;          // b*NN + k
  int b = col / NN, k = col - b * NN;
  int tid = threadIdx.x;         // j
  const float* hrow  = hb  + col * DD;   // uniform
  const float* harow = hAb + col * DD;
  const float* hTb   = hT  + b * NN + tid;
  const float* hATb  = hAT + b * NN + tid;
  float e0 = 0.f, e1 = 0.f;
#pragma unroll 4
  for (int cc = 0; cc < DD; cc += 2) {
    e0 += hATb[cc * 768] * hrow[cc] + hTb[cc * 768] * harow[cc];
    e1 += hATb[(cc + 1) * 768] * hrow[cc + 1] + hTb[(cc + 1) * 768] * harow[cc + 1];
  }
  float e = e0 + e1;
  float a = adj[col * NN + tid];   // adj symmetric
  __shared__ float red[6];
  float lmax = (a > 0.f) ? e : -3e38f;
#pragma unroll
  for (int off = 32; off > 0; off >>= 1) lmax = fmaxf(lmax, __shfl_down(lmax, off));
  int w = tid >> 6;
  if ((tid & 63) == 0) red[w] = lmax;
  __syncthreads();
  float m = red[0];
#pragma unroll
  for (int q = 1; q < 6; ++q) m = fmaxf(m, red[q]);
  float v = (a > 0.f) ? __expf(e - m) : 0.f;
  float s = v;
#pragma unroll
  for (int off = 32; off > 0; off >>= 1) s += __shfl_down(s, off);
  __syncthreads();
  if ((tid & 63) == 0) red[w] = s;
  __syncthreads();
  float d = 0.f;
#pragma unroll
  for (int q = 0; q < 6; ++q) d += red[q];
  att[(b * NN + tid) * NN + k] = v * a / d;   // row-major divergent store
}

// ================= k_out_hhA: 768 blocks x 256 thr, 1 row/block ============
// gated output(l) then h/hA(l+1) for the same row. Dims split 2-way in block.
__global__ __launch_bounds__(256) void k_out_hhA(
    const float* __restrict__ x, const float* __restrict__ hb,
    const float* __restrict__ att,
    const float* __restrict__ gW, const float* __restrict__ gb,
    const float* __restrict__ Wn, const float* __restrict__ Wbn,
    const float* __restrict__ An,
    float* __restrict__ xout,
    float* __restrict__ hbn, float* __restrict__ hAbn,
    float* __restrict__ hTn, float* __restrict__ hATn) {
  int r = blockIdx.x;            // global row
  int b = r / NN;
  int tid = threadIdx.x, c = tid & 127, jh = tid >> 7;
  __shared__ float ph[2][DD];
  __shared__ float redw[2];
  // ---- att@h, j-half per group
  const float4* ar4 = (const float4*)(att + r * NN) + jh * 48;
  const float* hp = hb + (b * NN + jh * 192) * DD + c;
  float q0 = 0.f, q1 = 0.f, q2 = 0.f, q3 = 0.f;
#pragma unroll 4
  for (int j4 = 0; j4 < 48; ++j4) {
    float4 av = ar4[j4];
    const float* hj = hp + j4 * 4 * DD;
    q0 += av.x * hj[0];
    q1 += av.y * hj[DD];
    q2 += av.z * hj[2 * DD];
    q3 += av.w * hj[3 * DD];
  }
  ph[jh][c] = (q0 + q1) + (q2 + q3);
  __syncthreads();
  float hpr = 0.f, xr = 0.f;
  if (tid < 128) {
    hpr = fmaxf(ph[0][c] + ph[1][c], 0.f);
    xr = x[r * DD + c];
    float v = xr * gW[c] + hpr * gW[DD + c];
#pragma unroll
    for (int off = 32; off > 0; off >>= 1) v += __shfl_down(v, off);
    if ((tid & 63) == 0) redw[tid >> 6] = v;
  }
  __syncthreads();
  if (tid < 128) {
    float coeff = sigmoidf_(redw[0] + redw[1] + gb[0]);
    xout[r * DD + c] = coeff * xr + (1.f - coeff) * hpr;
  }
  __syncthreads();
  // ---- h(l+1) = xout@Wn + Wbn, k-half per group
  const float* xb = xout + r * DD + jh * 64;
  const float* Wp = Wn + (jh * 64) * DD + c;
  float a0 = 0.f, a1 = 0.f;
#pragma unroll 4
  for (int k = 0; k < 64; k += 2) {
    a0 += xb[k] * Wp[k * DD];
    a1 += xb[k + 1] * Wp[(k + 1) * DD];
  }
  ph[jh][c] = a0 + a1;
  __syncthreads();
  if (tid < 128) {
    float hv = ph[0][c] + ph[1][c] + Wbn[c];
    hbn[r * DD + c] = hv; hTn[c * 768 + r] = hv;
  }
  __syncthreads();
  // ---- hA(l+1) = h@An
  const float* hbr = hbn + r * DD + jh * 64;
  const float* Ap = An + (jh * 64) * DD + c;
  a0 = 0.f; a1 = 0.f;
#pragma unroll 4
  for (int k = 0; k < 64; k += 2) {
    a0 += hbr[k] * Ap[k * DD];
    a1 += hbr[k + 1] * Ap[(k + 1) * DD];
  }
  ph[jh][c] = a0 + a1;
  __syncthreads();
  if (tid < 128) {
    float av = ph[0][c] + ph[1][c];
    hAbn[r * DD + c] = av; hATn[c * 768 + r] = av;
  }
}

// ================= k_out_proj: 768 blocks x 256 thr, 1 row/block ===========
// gated output(2) + intercept partial + ligand pair projection.
__global__ __launch_bounds__(256) void k_out_proj(
    const float* __restrict__ x, const float* __restrict__ hb,
    const float* __restrict__ att,
    const float* __restrict__ gW, const float* __restrict__ gb,
    const float* __restrict__ pW1, const float* __restrict__ pb1,
    const float* __restrict__ valid1,
    float* __restrict__ xout, float* __restrict__ p1, float* __restrict__ wsi) {
  int r = blockIdx.x;
  int b = r / NN;
  int tid = threadIdx.x, c = tid & 127, jh = tid >> 7;
  __shared__ float ph[2][DD];
  __shared__ float redw[2];
  const float4* ar4 = (const float4*)(att + r * NN) + jh * 48;
  const float* hp = hb + (b * NN + jh * 192) * DD + c;
  float q0 = 0.f, q1 = 0.f, q2 = 0.f, q3 = 0.f;
#pragma unroll 4
  for (int j4 = 0; j4 < 48; ++j4) {
    float4 av = ar4[j4];
    const float* hj = hp + j4 * 4 * DD;
    q0 += av.x * hj[0];
    q1 += av.y * hj[DD];
    q2 += av.z * hj[2 * DD];
    q3 += av.w * hj[3 * DD];
  }
  ph[jh][c] = (q0 + q1) + (q2 + q3);
  __syncthreads();
  float hpr = 0.f, xr = 0.f;
  if (tid < 128) {
    hpr = fmaxf(ph[0][c] + ph[1][c], 0.f);
    xr = x[r * DD + c];
    float v = xr * gW[c] + hpr * gW[DD + c];
#pragma unroll
    for (int off = 32; off > 0; off >>= 1) v += __shfl_down(v, off);
    if ((tid & 63) == 0) redw[tid >> 6] = v;
  }
  __syncthreads();
  if (tid < 128) {
    float coeff = sigmoidf_(redw[0] + redw[1] + gb[0]);
    float nv = coeff * xr + (1.f - coeff) * hpr;
    xout[r * DD + c] = nv;
    wsi[r * DD + c] = nv * valid1[r];
  }
  __syncthreads();
  // ligand projection for this row (x via block-uniform scalar path)
  const float* xbase = xout + r * DD;
  for (int o = tid; o < 640; o += 256) {
    int m = o >> 7, hc = o & 127;
    const float* Wcol = pW1 + (m * 256) * HH + hc;
    float a0 = 0.f, a1 = 0.f;
#pragma unroll 4
    for (int k = 0; k < DD; k += 2) {
      a0 += xbase[k] * Wcol[k * HH];
      a1 += xbase[k + 1] * Wcol[(k + 1) * HH];
    }
    p1[(r * 5 + m) * HH + hc] = a0 + a1 + pb1[m * HH + hc];
  }
}

// ================= k_energy: 512 blocks x 384 thr ==========================
// Block = 3-row tile x j-half(192). Threads: jp(0..191) x hh(H-half).
// Partner combine via LDS (one-shot), energies on hh==0 threads.
__global__ __launch_bounds__(384) void k_energy(
    const float* __restrict__ p1, const float* __restrict__ p2q,
    const float* __restrict__ W2, const float* __restrict__ b2,
    const float* __restrict__ dmv, const float* __restrict__ charge1,
    const float* __restrict__ charge2, const float* __restrict__ veps,
    const float* __restrict__ vsig, const float* __restrict__ valid1,
    const float* __restrict__ valid2, const float* __restrict__ nm1,
    const float* __restrict__ nm2, const float* __restrict__ vdw_coeff,
    float* __restrict__ out) {
  int blk = blockIdx.x, tid = threadIdx.x;
  int tile = blk >> 1, jh = blk & 1;
  int r0 = tile * 3;
  int b = r0 / NN;
  int jp = tid < 192 ? tid : tid - 192;
  int hh = tid < 192 ? 0 : 1;
  int j = jh * 192 + jp;
  int col = b * NN + j;
  const float* q0 = p1 + (r0 + 0) * 640;   // block-uniform -> scalar path
  const float* q1 = p1 + (r0 + 1) * 640;
  const float* q2 = p1 + (r0 + 2) * 640;
  const float4* p2q4 = (const float4*)p2q;
  float am[3][5];
#pragma unroll
  for (int m = 0; m < 5; ++m) {
    const float4* pc = p2q4 + (size_t)(m * 32 + hh * 16) * 768 + col;
    const float* w2m = W2 + m * HH + hh * 64;
    const float* x0 = q0 + m * HH + hh * 64;
    const float* x1 = q1 + m * HH + hh * 64;
    const float* x2 = q2 + m * HH + hh * 64;
    float a0 = 0.f, a1 = 0.f, a2 = 0.f;
#pragma unroll 4
    for (int hq = 0; hq < 16; ++hq) {
      float4 pv = pc[(size_t)hq * 768];
      float w0 = w2m[4 * hq], w1 = w2m[4 * hq + 1], w2v = w2m[4 * hq + 2], w3 = w2m[4 * hq + 3];
      a0 += fmaxf(x0[4 * hq] + pv.x, 0.f) * w0 + fmaxf(x0[4 * hq + 1] + pv.y, 0.f) * w1
          + fmaxf(x0[4 * hq + 2] + pv.z, 0.f) * w2v + fmaxf(x0[4 * hq + 3] + pv.w, 0.f) * w3;
      a1 += fmaxf(x1[4 * hq] + pv.x, 0.f) * w0 + fmaxf(x1[4 * hq + 1] + pv.y, 0.f) * w1
          + fmaxf(x1[4 * hq + 2] + pv.z, 0.f) * w2v + fmaxf(x1[4 * hq + 3] + pv.w, 0.f) * w3;
      a2 += fmaxf(x2[4 * hq] + pv.x, 0.f) * w0 + fmaxf(x2[4 * hq + 1] + pv.y, 0.f) * w1
          + fmaxf(x2[4 * hq + 2] + pv.z, 0.f) * w2v + fmaxf(x2[4 * hq + 3] + pv.w, 0.f) * w3;
    }
    am[0][m] = a0; am[1][m] = a1; am[2][m] = a2;
  }
  __shared__ float part[192][15];
  if (hh) {
#pragma unroll
    for (int t = 0; t < 3; ++t)
#pragma unroll
      for (int m = 0; m < 5; ++m) part[jp][t * 5 + m] = am[t][m];
  }
  __syncthreads();
  __shared__ float rec[3], rev[3];
  if (!hh) {
#pragma unroll
    for (int t = 0; t < 3; ++t)
#pragma unroll
      for (int m = 0; m < 5; ++m) am[t][m] += part[jp][t * 5 + m] + b2[m];
    float q2c = charge2[col], vv2 = valid2[col], n2 = nm2[col];
    float vc2 = vdw_coeff[0] * vdw_coeff[0];
    float ec_sum = 0.f, ev_sum = 0.f;
#pragma unroll
    for (int ti = 0; ti < 3; ++ti) {
      int gi = r0 + ti;
      int pidx = gi * NN + j;
      float dx = dmv[pidx * 3], dy = dmv[pidx * 3 + 1], dz = dmv[pidx * 3 + 2];
      float dm = sqrtf(dx * dx + dy * dy + dz * dz + 1e-10f);
      if (dm < 0.5f) dm = 1e10f;
      float cA = sigmoidf_(am[ti][0]);
      float cN = sigmoidf_(am[ti][1]) * 2.f + 1.f;
      float e_c = cA * charge1[gi] * q2c * __powf(1.f / dm, cN);
      e_c *= valid1[gi] * vv2;
      e_c = fminf(fmaxf(e_c, -100.f), 100.f);
      ec_sum += e_c;
      float vA = (sigmoidf_(am[ti][2]) * 0.6f + 0.7f) * vc2 * veps[pidx];
      float vB = tanhf_(am[ti][3]) * 0.6f + 0.7f;
      float vN = sigmoidf_(am[ti][4]) * 2.f + 5.f;
      float dm0 = vsig[pidx] * vB;
      if (dm0 < 1e-4f) dm0 = 1.f;
      float rr = __powf(dm0 / dm, vN);
      float e_v = vA * (rr * rr - 2.f * rr);
      e_v *= nm1[gi] * n2;
      e_v = fminf(e_v, 100.f);
      ev_sum += e_v;
    }
#pragma unroll
    for (int off = 32; off > 0; off >>= 1) {
      ec_sum += __shfl_down(ec_sum, off);
      ev_sum += __shfl_down(ev_sum, off);
    }
    if ((tid & 63) == 0) { rec[tid >> 6] = ec_sum; rev[tid >> 6] = ev_sum; }
  }
  __syncthreads();
  if (tid == 0) {
    atomicAdd(&out[b * 4 + 0], rec[0] + rec[1] + rec[2]);
    atomicAdd(&out[b * 4 + 1], rev[0] + rev[1] + rev[2]);
  }
}

// ================= k_fin: intercept MLP ====================================
__global__ __launch_bounds__(256) void k_fin(
    const float* __restrict__ wsi, const float* __restrict__ iW1,
    const float* __restrict__ ib1, const float* __restrict__ iW2,
    const float* __restrict__ ib2, float* __restrict__ out) {
  int tid = threadIdx.x, bb = tid >> 7, cc = tid & 127;
  __shared__ float hsf[2][DD];
  __shared__ float redf[2][2];
  float a0 = 0.f, a1 = 0.f;
  for (int q = 0; q < 384; q += 2) {
    a0 += wsi[(bb * 384 + q) * DD + cc];
    a1 += wsi[(bb * 384 + q + 1) * DD + cc];
  }
  hsf[bb][cc] = a0 + a1;
  __syncthreads();
  float hid = ib1[cc];
#pragma unroll 4
  for (int k = 0; k < DD; ++k) hid += hsf[bb][k] * iW1[k * HH + cc];
  hid = fmaxf(hid, 0.f);
  float v = hid * iW2[cc];
#pragma unroll
  for (int off = 32; off > 0; off >>= 1) v += __shfl_down(v, off);
  if ((tid & 63) == 0) redf[bb][(tid >> 6) & 1] = v;
  __syncthreads();
  if (tid < 2) out[tid * 4 + 3] = redf[tid][0] + redf[tid][1] + ib2[0];
}

// ---------------------------------------------------------------- launch
extern "C" void kernel_launch(void* const* d_in, const int* in_sizes, int n_in,
                              void* d_out, int out_size, void* d_ws, size_t ws_size,
                              hipStream_t stream) {
  (void)in_sizes; (void)n_in; (void)out_size; (void)ws_size;
  const float* h1         = (const float*)d_in[0];
  const float* h2         = (const float*)d_in[1];
  const float* adj1       = (const float*)d_in[2];
  const float* dmv        = (const float*)d_in[3];
  const float* charge1    = (const float*)d_in[4];
  const float* charge2    = (const float*)d_in[5];
  const float* veps       = (const float*)d_in[6];
  const float* vsig       = (const float*)d_in[7];
  const float* delta_uff  = (const float*)d_in[8];
  const float* valid1     = (const float*)d_in[9];
  const float* valid2     = (const float*)d_in[10];
  const float* nm1        = (const float*)d_in[11];
  const float* nm2        = (const float*)d_in[12];
  const float* node_W     = (const float*)d_in[13];
  const float* gat_W      = (const float*)d_in[14];
  const float* gat_Wb     = (const float*)d_in[15];
  const float* gat_A      = (const float*)d_in[16];
  const float* gat_gW     = (const float*)d_in[17];
  const float* gat_gb     = (const float*)d_in[18];
  const float* pW1        = (const float*)d_in[19];
  const float* pb1        = (const float*)d_in[20];
  const float* pW2        = (const float*)d_in[21];
  const float* pb2        = (const float*)d_in[22];
  const float* vdw_coeff  = (const float*)d_in[23];
  const float* duff_coeff = (const float*)d_in[24];
  const float* iW1        = (const float*)d_in[25];
  const float* ib1        = (const float*)d_in[26];
  const float* iW2        = (const float*)d_in[27];
  const float* ib2        = (const float*)d_in[28];
  float* out = (float*)d_out;

  float* ws = (float*)d_ws;
  const int RN = 768 * DD;  // 98304
  float* h1gA = ws;               // x ping-pong A
  float* h1gB = h1gA + RN;        // x ping-pong B
  float* h2g  = h1gB + RN;
  float* hb0  = h2g  + RN;
  float* hA0  = hb0  + RN;
  float* hT0  = hA0  + RN;
  float* hAT0 = hT0  + RN;
  float* hb1  = hAT0 + RN;
  float* hA1  = hb1  + RN;
  float* hT1  = hA1  + RN;
  float* hAT1 = hT1  + RN;
  float* att  = hAT1 + RN;            // 2*384*384
  float* p1   = att + 2 * NN * NN;    // 768*640
  float* p2q  = p1 + 768 * 640;       // 768*640 packed
  float* wsi  = p2q + 768 * 640;      // 768*128

  const int DD2 = DD * DD;

  k_start<<<dim3(768), dim3(256), 0, stream>>>(
      h1, h2, node_W, gat_W, gat_Wb, gat_A, pW1, delta_uff, duff_coeff,
      h1gA, h2g, hb0, hA0, hT0, hAT0, p2q, out);

  // layer 0
  k_att<<<dim3(768), dim3(384), 0, stream>>>(hb0, hA0, hT0, hAT0, adj1, att);
  k_out_hhA<<<dim3(768), dim3(256), 0, stream>>>(
      h1gA, hb0, att, gat_gW + 0, gat_gb + 0,
      gat_W + DD2, gat_Wb + DD, gat_A + DD2,
      h1gB, hb1, hA1, hT1, hAT1);
  // layer 1
  k_att<<<dim3(768), dim3(384), 0, stream>>>(hb1, hA1, hT1, hAT1, adj1, att);
  k_out_hhA<<<dim3(768), dim3(256), 0, stream>>>(
      h1gB, hb1, att, gat_gW + 2 * DD, gat_gb + 1,
      gat_W + 2 * DD2, gat_Wb + 2 * DD, gat_A + 2 * DD2,
      h1gA, hb0, hA0, hT0, hAT0);
  // layer 2
  k_att<<<dim3(768), dim3(384), 0, stream>>>(hb0, hA0, hT0, hAT0, adj1, att);
  k_out_proj<<<dim3(768), dim3(256), 0, stream>>>(
      h1gA, hb0, att, gat_gW + 4 * DD, gat_gb + 2,
      pW1, pb1, valid1, h1gB, p1, wsi);

  k_energy<<<dim3(512), dim3(384), 0, stream>>>(
      p1, p2q, pW2, pb2, dmv, charge1, charge2, veps, vsig,
      valid1, valid2, nm1, nm2, vdw_coeff, out);
  k_fin<<<dim3(1), dim3(256), 0, stream>>>(wsi, iW1, ib1, iW2, ib2, out);
}

// Round 10
// 294.145 us; speedup vs baseline: 1.1097x; 1.1097x over previous
//
#include <hip/hip_runtime.h>
#include <math.h>

#define NN 384
#define DD 128
#define HH 128

__device__ __forceinline__ float sigmoidf_(float x) { return 1.f / (1.f + __expf(-x)); }
__device__ __forceinline__ float tanhf_(float x)    { return 1.f - 2.f / (__expf(2.f * x) + 1.f); }

// ================= k_start: 768 blocks x 256 thr, 2 rows/block ============
// Blocks 0..383: ligand embed + h/hA(layer0). Blocks 384..767: protein embed
// + pair projection (p2q packed).
__global__ __launch_bounds__(256) void k_start(
    const float* __restrict__ h1, const float* __restrict__ h2,
    const float* __restrict__ nW,
    const float* __restrict__ W, const float* __restrict__ Wb, const float* __restrict__ A,
    const float* __restrict__ pW1,
    const float* __restrict__ delta_uff, const float* __restrict__ duff,
    float* __restrict__ h1g, float* __restrict__ h2g,
    float* __restrict__ hb, float* __restrict__ hAb,
    float* __restrict__ hT, float* __restrict__ hAT,
    float* __restrict__ p2q, float* __restrict__ out) {
  int blk = blockIdx.x, tid = threadIdx.x, c = tid & 127, g = tid >> 7;  // g in {0,1}
  if (blk == 0 && tid < 8) {
    int bb = tid >> 2, cc = tid & 3;
    out[tid] = (cc == 2) ? duff[0] * duff[0] * delta_uff[bb] : 0.f;
  }
  if (blk < 384) {
    int r = blk * 2 + g;
    const float* xr = h1 + r * 54;
    float acc = 0.f;
#pragma unroll 6
    for (int k = 0; k < 54; ++k) acc += xr[k] * nW[k * DD + c];
    h1g[r * DD + c] = acc;
    __syncthreads();
    const float4* xr4 = (const float4*)(h1g + r * DD);
    float a0 = 0.f, a1 = 0.f;
#pragma unroll 4
    for (int k4 = 0; k4 < DD / 4; ++k4) {
      float4 xv = xr4[k4]; int k = 4 * k4;
      a0 += xv.x * W[k * DD + c] + xv.z * W[(k + 2) * DD + c];
      a1 += xv.y * W[(k + 1) * DD + c] + xv.w * W[(k + 3) * DD + c];
    }
    float hv = a0 + a1 + Wb[c];
    hb[r * DD + c] = hv; hT[c * 768 + r] = hv;
    __syncthreads();
    const float4* hr4 = (const float4*)(hb + r * DD);
    a0 = 0.f; a1 = 0.f;
#pragma unroll 4
    for (int k4 = 0; k4 < DD / 4; ++k4) {
      float4 xv = hr4[k4]; int k = 4 * k4;
      a0 += xv.x * A[k * DD + c] + xv.z * A[(k + 2) * DD + c];
      a1 += xv.y * A[(k + 1) * DD + c] + xv.w * A[(k + 3) * DD + c];
    }
    float av = a0 + a1;
    hAb[r * DD + c] = av; hAT[c * 768 + r] = av;
  } else {
    int r0 = (blk - 384) * 2;
    int r = r0 + g;
    const float* xr = h2 + r * 54;
    float acc = 0.f;
#pragma unroll 6
    for (int k = 0; k < 54; ++k) acc += xr[k] * nW[k * DD + c];
    h2g[r * DD + c] = acc;
    __syncthreads();
    const float* xbase = h2g + r0 * DD;  // block-uniform -> scalar path
    for (int o = tid; o < 640; o += 256) {
      int m = o >> 7, hc = o & 127;
      const float* Wcol = pW1 + (m * 256 + 128) * HH + hc;
      float a0 = 0.f, a1 = 0.f;
#pragma unroll 4
      for (int k = 0; k < DD; ++k) {
        float w = Wcol[k * HH];
        a0 += xbase[k] * w;
        a1 += xbase[DD + k] * w;
      }
      float* dst = p2q + (size_t)((m * 32 + (hc >> 2)) * 768 + r0) * 4 + (hc & 3);
      dst[0] = a0; dst[4] = a1;
    }
  }
}

// ================= k_att: 768 blocks x 384 thr, 1 column/block =============
// adj (HBM-cold) loaded FIRST so it's in flight during the 128-iter dot loop.
__global__ __launch_bounds__(384) void k_att(
    const float* __restrict__ hb, const float* __restrict__ hAb,
    const float* __restrict__ hT, const float* __restrict__ hAT,
    const float* __restrict__ adj, float* __restrict__ att) {
  int col = blockIdx.x;          // b*NN + k
  int b = col / NN, k = col - b * NN;
  int tid = threadIdx.x;         // j
  float a = adj[col * NN + tid];   // adj symmetric; prefetch (HBM)
  const float* hrow  = hb  + col * DD;   // uniform
  const float* harow = hAb + col * DD;
  const float* hTb   = hT  + b * NN + tid;
  const float* hATb  = hAT + b * NN + tid;
  float e0 = 0.f, e1 = 0.f;
#pragma unroll 4
  for (int cc = 0; cc < DD; cc += 2) {
    e0 += hATb[cc * 768] * hrow[cc] + hTb[cc * 768] * harow[cc];
    e1 += hATb[(cc + 1) * 768] * hrow[cc + 1] + hTb[(cc + 1) * 768] * harow[cc + 1];
  }
  float e = e0 + e1;
  __shared__ float red[6];
  float lmax = (a > 0.f) ? e : -3e38f;
#pragma unroll
  for (int off = 32; off > 0; off >>= 1) lmax = fmaxf(lmax, __shfl_down(lmax, off));
  int w = tid >> 6;
  if ((tid & 63) == 0) red[w] = lmax;
  __syncthreads();
  float m = red[0];
#pragma unroll
  for (int q = 1; q < 6; ++q) m = fmaxf(m, red[q]);
  float v = (a > 0.f) ? __expf(e - m) : 0.f;
  float s = v;
#pragma unroll
  for (int off = 32; off > 0; off >>= 1) s += __shfl_down(s, off);
  __syncthreads();
  if ((tid & 63) == 0) red[w] = s;
  __syncthreads();
  float d = 0.f;
#pragma unroll
  for (int q = 0; q < 6; ++q) d += red[q];
  att[(b * NN + tid) * NN + k] = v * a / d;   // row-major divergent store
}

// ================= k_out_hhA: 768 blocks x 256 thr, 1 row/block ============
// x/gW hoisted before the att@h loop (prefetch).
__global__ __launch_bounds__(256) void k_out_hhA(
    const float* __restrict__ x, const float* __restrict__ hb,
    const float* __restrict__ att,
    const float* __restrict__ gW, const float* __restrict__ gb,
    const float* __restrict__ Wn, const float* __restrict__ Wbn,
    const float* __restrict__ An,
    float* __restrict__ xout,
    float* __restrict__ hbn, float* __restrict__ hAbn,
    float* __restrict__ hTn, float* __restrict__ hATn) {
  int r = blockIdx.x;            // global row
  int b = r / NN;
  int tid = threadIdx.x, c = tid & 127, jh = tid >> 7;
  __shared__ float ph[2][DD];
  __shared__ float redw[2];
  float xr = x[r * DD + c];        // prefetch
  float g1 = gW[c], g2 = gW[DD + c], gbv = gb[0];
  const float4* ar4 = (const float4*)(att + r * NN) + jh * 48;
  const float* hp = hb + (b * NN + jh * 192) * DD + c;
  float q0 = 0.f, q1 = 0.f, q2 = 0.f, q3 = 0.f;
#pragma unroll 4
  for (int j4 = 0; j4 < 48; ++j4) {
    float4 av = ar4[j4];
    const float* hj = hp + j4 * 4 * DD;
    q0 += av.x * hj[0];
    q1 += av.y * hj[DD];
    q2 += av.z * hj[2 * DD];
    q3 += av.w * hj[3 * DD];
  }
  ph[jh][c] = (q0 + q1) + (q2 + q3);
  __syncthreads();
  float hpr = 0.f;
  if (tid < 128) {
    hpr = fmaxf(ph[0][c] + ph[1][c], 0.f);
    float v = xr * g1 + hpr * g2;
#pragma unroll
    for (int off = 32; off > 0; off >>= 1) v += __shfl_down(v, off);
    if ((tid & 63) == 0) redw[tid >> 6] = v;
  }
  __syncthreads();
  if (tid < 128) {
    float coeff = sigmoidf_(redw[0] + redw[1] + gbv);
    xout[r * DD + c] = coeff * xr + (1.f - coeff) * hpr;
  }
  __syncthreads();
  const float* xb = xout + r * DD + jh * 64;
  const float* Wp = Wn + (jh * 64) * DD + c;
  float a0 = 0.f, a1 = 0.f;
#pragma unroll 4
  for (int k = 0; k < 64; k += 2) {
    a0 += xb[k] * Wp[k * DD];
    a1 += xb[k + 1] * Wp[(k + 1) * DD];
  }
  ph[jh][c] = a0 + a1;
  __syncthreads();
  if (tid < 128) {
    float hv = ph[0][c] + ph[1][c] + Wbn[c];
    hbn[r * DD + c] = hv; hTn[c * 768 + r] = hv;
  }
  __syncthreads();
  const float* hbr = hbn + r * DD + jh * 64;
  const float* Ap = An + (jh * 64) * DD + c;
  a0 = 0.f; a1 = 0.f;
#pragma unroll 4
  for (int k = 0; k < 64; k += 2) {
    a0 += hbr[k] * Ap[k * DD];
    a1 += hbr[k + 1] * Ap[(k + 1) * DD];
  }
  ph[jh][c] = a0 + a1;
  __syncthreads();
  if (tid < 128) {
    float av = ph[0][c] + ph[1][c];
    hAbn[r * DD + c] = av; hATn[c * 768 + r] = av;
  }
}

// ================= k_out_proj: 768 blocks x 256 thr, 1 row/block ===========
__global__ __launch_bounds__(256) void k_out_proj(
    const float* __restrict__ x, const float* __restrict__ hb,
    const float* __restrict__ att,
    const float* __restrict__ gW, const float* __restrict__ gb,
    const float* __restrict__ pW1, const float* __restrict__ pb1,
    const float* __restrict__ valid1,
    float* __restrict__ xout, float* __restrict__ p1, float* __restrict__ wsi) {
  int r = blockIdx.x;
  int b = r / NN;
  int tid = threadIdx.x, c = tid & 127, jh = tid >> 7;
  __shared__ float ph[2][DD];
  __shared__ float redw[2];
  float xr = x[r * DD + c];        // prefetch
  float g1 = gW[c], g2 = gW[DD + c], gbv = gb[0];
  float vld = valid1[r];
  const float4* ar4 = (const float4*)(att + r * NN) + jh * 48;
  const float* hp = hb + (b * NN + jh * 192) * DD + c;
  float q0 = 0.f, q1 = 0.f, q2 = 0.f, q3 = 0.f;
#pragma unroll 4
  for (int j4 = 0; j4 < 48; ++j4) {
    float4 av = ar4[j4];
    const float* hj = hp + j4 * 4 * DD;
    q0 += av.x * hj[0];
    q1 += av.y * hj[DD];
    q2 += av.z * hj[2 * DD];
    q3 += av.w * hj[3 * DD];
  }
  ph[jh][c] = (q0 + q1) + (q2 + q3);
  __syncthreads();
  float hpr = 0.f;
  if (tid < 128) {
    hpr = fmaxf(ph[0][c] + ph[1][c], 0.f);
    float v = xr * g1 + hpr * g2;
#pragma unroll
    for (int off = 32; off > 0; off >>= 1) v += __shfl_down(v, off);
    if ((tid & 63) == 0) redw[tid >> 6] = v;
  }
  __syncthreads();
  if (tid < 128) {
    float coeff = sigmoidf_(redw[0] + redw[1] + gbv);
    float nv = coeff * xr + (1.f - coeff) * hpr;
    xout[r * DD + c] = nv;
    wsi[r * DD + c] = nv * vld;
  }
  __syncthreads();
  const float* xbase = xout + r * DD;   // block-uniform -> scalar path
  for (int o = tid; o < 640; o += 256) {
    int m = o >> 7, hc = o & 127;
    const float* Wcol = pW1 + (m * 256) * HH + hc;
    float a0 = 0.f, a1 = 0.f;
#pragma unroll 4
    for (int k = 0; k < DD; k += 2) {
      a0 += xbase[k] * Wcol[k * HH];
      a1 += xbase[k + 1] * Wcol[(k + 1) * HH];
    }
    p1[(r * 5 + m) * HH + hc] = a0 + a1 + pb1[m * HH + hc];
  }
}

// ================= k_energy: 385 blocks x 384 thr ==========================
// Blocks 0..383: TI=2 ligand rows, lane = j (full 384), full H per lane
// (round-6 42µs structure). HBM tail operands (dmv/veps/vsig/charge/masks)
// loaded FIRST so their ~900-cyc latency overlaps the MLP loop.
// Block 384: intercept MLP (independent of energy blocks).
__global__ __launch_bounds__(384) void k_energy(
    const float* __restrict__ p1, const float* __restrict__ p2q,
    const float* __restrict__ W2, const float* __restrict__ b2,
    const float* __restrict__ dmv, const float* __restrict__ charge1,
    const float* __restrict__ charge2, const float* __restrict__ veps,
    const float* __restrict__ vsig, const float* __restrict__ valid1,
    const float* __restrict__ valid2, const float* __restrict__ nm1,
    const float* __restrict__ nm2, const float* __restrict__ vdw_coeff,
    const float* __restrict__ wsi, const float* __restrict__ iW1,
    const float* __restrict__ ib1, const float* __restrict__ iW2,
    const float* __restrict__ ib2, float* __restrict__ out) {
  int blk = blockIdx.x, tid = threadIdx.x;
  if (blk >= 384) {   // ---- intercept finisher
    if (tid < 256) {
      int bb = tid >> 7, cc = tid & 127;
      __shared__ float hsf[2][DD];
      __shared__ float redf[2][2];
      float a0 = 0.f, a1 = 0.f;
      for (int q = 0; q < 384; q += 2) {
        a0 += wsi[(bb * 384 + q) * DD + cc];
        a1 += wsi[(bb * 384 + q + 1) * DD + cc];
      }
      hsf[bb][cc] = a0 + a1;
      __syncthreads();
      float hid = ib1[cc];
#pragma unroll 4
      for (int k = 0; k < DD; ++k) hid += hsf[bb][k] * iW1[k * HH + cc];
      hid = fmaxf(hid, 0.f);
      float v = hid * iW2[cc];
#pragma unroll
      for (int off = 32; off > 0; off >>= 1) v += __shfl_down(v, off);
      if ((tid & 63) == 0) redf[bb][(tid >> 6) & 1] = v;
      __syncthreads();
      if (tid < 2) out[tid * 4 + 3] = redf[tid][0] + redf[tid][1] + ib2[0];
    }
    return;
  }
  int r0 = blk * 2;
  int b = r0 / NN;
  int j = tid;
  int col = b * NN + j;
  // ---- prefetch HBM tail operands (independent; in flight during MLP loop)
  int p0 = r0 * NN + j, pI = p0 + NN;
  float dx0 = dmv[3 * p0], dy0 = dmv[3 * p0 + 1], dz0 = dmv[3 * p0 + 2];
  float dx1 = dmv[3 * pI], dy1 = dmv[3 * pI + 1], dz1 = dmv[3 * pI + 2];
  float ve0 = veps[p0], ve1 = veps[pI];
  float vs0 = vsig[p0], vs1 = vsig[pI];
  float q2c = charge2[col], vv2 = valid2[col], n2 = nm2[col];
  // uniform row-side (scalar regs)
  float c1a = charge1[r0], c1b = charge1[r0 + 1];
  float vaa = valid1[r0], vab = valid1[r0 + 1];
  float naa = nm1[r0], nab = nm1[r0 + 1];
  float vc2 = vdw_coeff[0] * vdw_coeff[0];

  // ---- pair MLP (m-outer, full H, scalar-broadcast p1/W2, coalesced p2q)
  const float* q0 = p1 + (r0 + 0) * 640;   // uniform -> s_load
  const float* q1 = p1 + (r0 + 1) * 640;
  const float4* p2q4 = (const float4*)p2q;
  float acc0[5], acc1[5];
#pragma unroll
  for (int m = 0; m < 5; ++m) {
    const float4* pc = p2q4 + (size_t)(m * 32) * 768 + col;
    const float* x0m = q0 + m * HH;
    const float* x1m = q1 + m * HH;
    const float* w2m = W2 + m * HH;
    float a0 = 0.f, a1 = 0.f;
#pragma unroll 8
    for (int hq = 0; hq < 32; ++hq) {
      float4 pv = pc[(size_t)hq * 768];
      float w0 = w2m[4 * hq], w1 = w2m[4 * hq + 1];
      float w2v = w2m[4 * hq + 2], w3 = w2m[4 * hq + 3];
      a0 += fmaxf(x0m[4 * hq] + pv.x, 0.f) * w0 + fmaxf(x0m[4 * hq + 1] + pv.y, 0.f) * w1
          + fmaxf(x0m[4 * hq + 2] + pv.z, 0.f) * w2v + fmaxf(x0m[4 * hq + 3] + pv.w, 0.f) * w3;
      a1 += fmaxf(x1m[4 * hq] + pv.x, 0.f) * w0 + fmaxf(x1m[4 * hq + 1] + pv.y, 0.f) * w1
          + fmaxf(x1m[4 * hq + 2] + pv.z, 0.f) * w2v + fmaxf(x1m[4 * hq + 3] + pv.w, 0.f) * w3;
    }
    acc0[m] = a0 + b2[m]; acc1[m] = a1 + b2[m];
  }

  // ---- energies (operands already resident)
  float ec_sum = 0.f, ev_sum = 0.f;
  {
    float dm = sqrtf(dx0 * dx0 + dy0 * dy0 + dz0 * dz0 + 1e-10f);
    if (dm < 0.5f) dm = 1e10f;
    float cA = sigmoidf_(acc0[0]);
    float cN = sigmoidf_(acc0[1]) * 2.f + 1.f;
    float e_c = cA * c1a * q2c * __powf(1.f / dm, cN);
    e_c *= vaa * vv2;
    ec_sum += fminf(fmaxf(e_c, -100.f), 100.f);
    float vA = (sigmoidf_(acc0[2]) * 0.6f + 0.7f) * vc2 * ve0;
    float vB = tanhf_(acc0[3]) * 0.6f + 0.7f;
    float vN = sigmoidf_(acc0[4]) * 2.f + 5.f;
    float dm0 = vs0 * vB;
    if (dm0 < 1e-4f) dm0 = 1.f;
    float rr = __powf(dm0 / dm, vN);
    float e_v = vA * (rr * rr - 2.f * rr) * naa * n2;
    ev_sum += fminf(e_v, 100.f);
  }
  {
    float dm = sqrtf(dx1 * dx1 + dy1 * dy1 + dz1 * dz1 + 1e-10f);
    if (dm < 0.5f) dm = 1e10f;
    float cA = sigmoidf_(acc1[0]);
    float cN = sigmoidf_(acc1[1]) * 2.f + 1.f;
    float e_c = cA * c1b * q2c * __powf(1.f / dm, cN);
    e_c *= vab * vv2;
    ec_sum += fminf(fmaxf(e_c, -100.f), 100.f);
    float vA = (sigmoidf_(acc1[2]) * 0.6f + 0.7f) * vc2 * ve1;
    float vB = tanhf_(acc1[3]) * 0.6f + 0.7f;
    float vN = sigmoidf_(acc1[4]) * 2.f + 5.f;
    float dm0 = vs1 * vB;
    if (dm0 < 1e-4f) dm0 = 1.f;
    float rr = __powf(dm0 / dm, vN);
    float e_v = vA * (rr * rr - 2.f * rr) * nab * n2;
    ev_sum += fminf(e_v, 100.f);
  }
#pragma unroll
  for (int off = 32; off > 0; off >>= 1) {
    ec_sum += __shfl_down(ec_sum, off);
    ev_sum += __shfl_down(ev_sum, off);
  }
  __shared__ float rec[6], rev[6];
  if ((tid & 63) == 0) { rec[tid >> 6] = ec_sum; rev[tid >> 6] = ev_sum; }
  __syncthreads();
  if (tid == 0) {
    float a = 0.f, c = 0.f;
#pragma unroll
    for (int w = 0; w < 6; ++w) { a += rec[w]; c += rev[w]; }
    atomicAdd(&out[b * 4 + 0], a);
    atomicAdd(&out[b * 4 + 1], c);
  }
}

// ---------------------------------------------------------------- launch
extern "C" void kernel_launch(void* const* d_in, const int* in_sizes, int n_in,
                              void* d_out, int out_size, void* d_ws, size_t ws_size,
                              hipStream_t stream) {
  (void)in_sizes; (void)n_in; (void)out_size; (void)ws_size;
  const float* h1         = (const float*)d_in[0];
  const float* h2         = (const float*)d_in[1];
  const float* adj1       = (const float*)d_in[2];
  const float* dmv        = (const float*)d_in[3];
  const float* charge1    = (const float*)d_in[4];
  const float* charge2    = (const float*)d_in[5];
  const float* veps       = (const float*)d_in[6];
  const float* vsig       = (const float*)d_in[7];
  const float* delta_uff  = (const float*)d_in[8];
  const float* valid1     = (const float*)d_in[9];
  const float* valid2     = (const float*)d_in[10];
  const float* nm1        = (const float*)d_in[11];
  const float* nm2        = (const float*)d_in[12];
  const float* node_W     = (const float*)d_in[13];
  const float* gat_W      = (const float*)d_in[14];
  const float* gat_Wb     = (const float*)d_in[15];
  const float* gat_A      = (const float*)d_in[16];
  const float* gat_gW     = (const float*)d_in[17];
  const float* gat_gb     = (const float*)d_in[18];
  const float* pW1        = (const float*)d_in[19];
  const float* pb1        = (const float*)d_in[20];
  const float* pW2        = (const float*)d_in[21];
  const float* pb2        = (const float*)d_in[22];
  const float* vdw_coeff  = (const float*)d_in[23];
  const float* duff_coeff = (const float*)d_in[24];
  const float* iW1        = (const float*)d_in[25];
  const float* ib1        = (const float*)d_in[26];
  const float* iW2        = (const float*)d_in[27];
  const float* ib2        = (const float*)d_in[28];
  float* out = (float*)d_out;

  float* ws = (float*)d_ws;
  const int RN = 768 * DD;  // 98304
  float* h1gA = ws;               // x ping-pong A
  float* h1gB = h1gA + RN;        // x ping-pong B
  float* h2g  = h1gB + RN;
  float* hb0  = h2g  + RN;
  float* hA0  = hb0  + RN;
  float* hT0  = hA0  + RN;
  float* hAT0 = hT0  + RN;
  float* hb1  = hAT0 + RN;
  float* hA1  = hb1  + RN;
  float* hT1  = hA1  + RN;
  float* hAT1 = hT1  + RN;
  float* att  = hAT1 + RN;            // 2*384*384
  float* p1   = att + 2 * NN * NN;    // 768*640
  float* p2q  = p1 + 768 * 640;       // 768*640 packed
  float* wsi  = p2q + 768 * 640;      // 768*128

  const int DD2 = DD * DD;

  k_start<<<dim3(768), dim3(256), 0, stream>>>(
      h1, h2, node_W, gat_W, gat_Wb, gat_A, pW1, delta_uff, duff_coeff,
      h1gA, h2g, hb0, hA0, hT0, hAT0, p2q, out);

  // layer 0
  k_att<<<dim3(768), dim3(384), 0, stream>>>(hb0, hA0, hT0, hAT0, adj1, att);
  k_out_hhA<<<dim3(768), dim3(256), 0, stream>>>(
      h1gA, hb0, att, gat_gW + 0, gat_gb + 0,
      gat_W + DD2, gat_Wb + DD, gat_A + DD2,
      h1gB, hb1, hA1, hT1, hAT1);
  // layer 1
  k_att<<<dim3(768), dim3(384), 0, stream>>>(hb1, hA1, hT1, hAT1, adj1, att);
  k_out_hhA<<<dim3(768), dim3(256), 0, stream>>>(
      h1gB, hb1, att, gat_gW + 2 * DD, gat_gb + 1,
      gat_W + 2 * DD2, gat_Wb + 2 * DD, gat_A + 2 * DD2,
      h1gA, hb0, hA0, hT0, hAT0);
  // layer 2
  k_att<<<dim3(768), dim3(384), 0, stream>>>(hb0, hA0, hT0, hAT0, adj1, att);
  k_out_proj<<<dim3(768), dim3(256), 0, stream>>>(
      h1gA, hb0, att, gat_gW + 4 * DD, gat_gb + 2,
      pW1, pb1, valid1, h1gB, p1, wsi);

  k_energy<<<dim3(385), dim3(384), 0, stream>>>(
      p1, p2q, pW2, pb2, dmv, charge1, charge2, veps, vsig,
      valid1, valid2, nm1, nm2, vdw_coeff, wsi, iW1, ib1, iW2, ib2, out);
}

// Round 11
// 285.303 us; speedup vs baseline: 1.1441x; 1.0310x over previous
//
#include <hip/hip_runtime.h>
#include <math.h>

#define NN 384
#define DD 128
#define HH 128

__device__ __forceinline__ float sigmoidf_(float x) { return 1.f / (1.f + __expf(-x)); }
__device__ __forceinline__ float tanhf_(float x)    { return 1.f - 2.f / (__expf(2.f * x) + 1.f); }

// ================= k_start: 768 blocks x 256 thr, 2 rows/block ============
// Blocks 0..383: ligand embed + h/hA(layer0). Blocks 384..767: protein embed
// only (protein projection moved next to k_energy for p2q L2 locality).
__global__ __launch_bounds__(256) void k_start(
    const float* __restrict__ h1, const float* __restrict__ h2,
    const float* __restrict__ nW,
    const float* __restrict__ W, const float* __restrict__ Wb, const float* __restrict__ A,
    const float* __restrict__ delta_uff, const float* __restrict__ duff,
    float* __restrict__ h1g, float* __restrict__ h2g,
    float* __restrict__ hb, float* __restrict__ hAb,
    float* __restrict__ hT, float* __restrict__ hAT,
    float* __restrict__ out) {
  int blk = blockIdx.x, tid = threadIdx.x, c = tid & 127, g = tid >> 7;  // g in {0,1}
  if (blk == 0 && tid < 8) {
    int bb = tid >> 2, cc = tid & 3;
    out[tid] = (cc == 2) ? duff[0] * duff[0] * delta_uff[bb] : 0.f;
  }
  if (blk < 384) {
    int r = blk * 2 + g;
    const float* xr = h1 + r * 54;
    float acc = 0.f;
#pragma unroll 6
    for (int k = 0; k < 54; ++k) acc += xr[k] * nW[k * DD + c];
    h1g[r * DD + c] = acc;
    __syncthreads();
    const float4* xr4 = (const float4*)(h1g + r * DD);
    float a0 = 0.f, a1 = 0.f;
#pragma unroll 4
    for (int k4 = 0; k4 < DD / 4; ++k4) {
      float4 xv = xr4[k4]; int k = 4 * k4;
      a0 += xv.x * W[k * DD + c] + xv.z * W[(k + 2) * DD + c];
      a1 += xv.y * W[(k + 1) * DD + c] + xv.w * W[(k + 3) * DD + c];
    }
    float hv = a0 + a1 + Wb[c];
    hb[r * DD + c] = hv; hT[c * 768 + r] = hv;
    __syncthreads();
    const float4* hr4 = (const float4*)(hb + r * DD);
    a0 = 0.f; a1 = 0.f;
#pragma unroll 4
    for (int k4 = 0; k4 < DD / 4; ++k4) {
      float4 xv = hr4[k4]; int k = 4 * k4;
      a0 += xv.x * A[k * DD + c] + xv.z * A[(k + 2) * DD + c];
      a1 += xv.y * A[(k + 1) * DD + c] + xv.w * A[(k + 3) * DD + c];
    }
    float av = a0 + a1;
    hAb[r * DD + c] = av; hAT[c * 768 + r] = av;
  } else {
    int r = (blk - 384) * 2 + g;
    const float* xr = h2 + r * 54;
    float acc = 0.f;
#pragma unroll 6
    for (int k = 0; k < 54; ++k) acc += xr[k] * nW[k * DD + c];
    h2g[r * DD + c] = acc;
  }
}

// ================= k_att: 768 blocks x 384 thr, 1 column/block =============
// adj (HBM-cold) prefetched; 4 independent accumulator chains for load ILP.
__global__ __launch_bounds__(384) void k_att(
    const float* __restrict__ hb, const float* __restrict__ hAb,
    const float* __restrict__ hT, const float* __restrict__ hAT,
    const float* __restrict__ adj, float* __restrict__ att) {
  int col = blockIdx.x;          // b*NN + k
  int b = col / NN, k = col - b * NN;
  int tid = threadIdx.x;         // j
  float a = adj[col * NN + tid];   // adj symmetric; prefetch (HBM)
  const float* hrow  = hb  + col * DD;   // uniform
  const float* harow = hAb + col * DD;
  const float* hTb   = hT  + b * NN + tid;
  const float* hATb  = hAT + b * NN + tid;
  float e0 = 0.f, e1 = 0.f, e2 = 0.f, e3 = 0.f;
#pragma unroll 4
  for (int cc = 0; cc < DD; cc += 4) {
    e0 += hATb[cc * 768] * hrow[cc] + hTb[cc * 768] * harow[cc];
    e1 += hATb[(cc + 1) * 768] * hrow[cc + 1] + hTb[(cc + 1) * 768] * harow[cc + 1];
    e2 += hATb[(cc + 2) * 768] * hrow[cc + 2] + hTb[(cc + 2) * 768] * harow[cc + 2];
    e3 += hATb[(cc + 3) * 768] * hrow[cc + 3] + hTb[(cc + 3) * 768] * harow[cc + 3];
  }
  float e = (e0 + e1) + (e2 + e3);
  __shared__ float red[6];
  float lmax = (a > 0.f) ? e : -3e38f;
#pragma unroll
  for (int off = 32; off > 0; off >>= 1) lmax = fmaxf(lmax, __shfl_down(lmax, off));
  int w = tid >> 6;
  if ((tid & 63) == 0) red[w] = lmax;
  __syncthreads();
  float m = red[0];
#pragma unroll
  for (int q = 1; q < 6; ++q) m = fmaxf(m, red[q]);
  float v = (a > 0.f) ? __expf(e - m) : 0.f;
  float s = v;
#pragma unroll
  for (int off = 32; off > 0; off >>= 1) s += __shfl_down(s, off);
  __syncthreads();
  if ((tid & 63) == 0) red[w] = s;
  __syncthreads();
  float d = 0.f;
#pragma unroll
  for (int q = 0; q < 6; ++q) d += red[q];
  att[(b * NN + tid) * NN + k] = v * a / d;   // row-major divergent store
}

// ================= k_out_hhA: 768 blocks x 256 thr, 1 row/block ============
__global__ __launch_bounds__(256) void k_out_hhA(
    const float* __restrict__ x, const float* __restrict__ hb,
    const float* __restrict__ att,
    const float* __restrict__ gW, const float* __restrict__ gb,
    const float* __restrict__ Wn, const float* __restrict__ Wbn,
    const float* __restrict__ An,
    float* __restrict__ xout,
    float* __restrict__ hbn, float* __restrict__ hAbn,
    float* __restrict__ hTn, float* __restrict__ hATn) {
  int r = blockIdx.x;            // global row
  int b = r / NN;
  int tid = threadIdx.x, c = tid & 127, jh = tid >> 7;
  __shared__ float ph[2][DD];
  __shared__ float redw[2];
  float xr = x[r * DD + c];        // prefetch
  float g1 = gW[c], g2 = gW[DD + c], gbv = gb[0];
  const float4* ar4 = (const float4*)(att + r * NN) + jh * 48;
  const float* hp = hb + (b * NN + jh * 192) * DD + c;
  float q0 = 0.f, q1 = 0.f, q2 = 0.f, q3 = 0.f;
#pragma unroll 4
  for (int j4 = 0; j4 < 48; ++j4) {
    float4 av = ar4[j4];
    const float* hj = hp + j4 * 4 * DD;
    q0 += av.x * hj[0];
    q1 += av.y * hj[DD];
    q2 += av.z * hj[2 * DD];
    q3 += av.w * hj[3 * DD];
  }
  ph[jh][c] = (q0 + q1) + (q2 + q3);
  __syncthreads();
  float hpr = 0.f;
  if (tid < 128) {
    hpr = fmaxf(ph[0][c] + ph[1][c], 0.f);
    float v = xr * g1 + hpr * g2;
#pragma unroll
    for (int off = 32; off > 0; off >>= 1) v += __shfl_down(v, off);
    if ((tid & 63) == 0) redw[tid >> 6] = v;
  }
  __syncthreads();
  if (tid < 128) {
    float coeff = sigmoidf_(redw[0] + redw[1] + gbv);
    xout[r * DD + c] = coeff * xr + (1.f - coeff) * hpr;
  }
  __syncthreads();
  const float* xb = xout + r * DD + jh * 64;
  const float* Wp = Wn + (jh * 64) * DD + c;
  float a0 = 0.f, a1 = 0.f;
#pragma unroll 4
  for (int k = 0; k < 64; k += 2) {
    a0 += xb[k] * Wp[k * DD];
    a1 += xb[k + 1] * Wp[(k + 1) * DD];
  }
  ph[jh][c] = a0 + a1;
  __syncthreads();
  if (tid < 128) {
    float hv = ph[0][c] + ph[1][c] + Wbn[c];
    hbn[r * DD + c] = hv; hTn[c * 768 + r] = hv;
  }
  __syncthreads();
  const float* hbr = hbn + r * DD + jh * 64;
  const float* Ap = An + (jh * 64) * DD + c;
  a0 = 0.f; a1 = 0.f;
#pragma unroll 4
  for (int k = 0; k < 64; k += 2) {
    a0 += hbr[k] * Ap[k * DD];
    a1 += hbr[k + 1] * Ap[(k + 1) * DD];
  }
  ph[jh][c] = a0 + a1;
  __syncthreads();
  if (tid < 128) {
    float av = ph[0][c] + ph[1][c];
    hAbn[r * DD + c] = av; hATn[c * 768 + r] = av;
  }
}

// ================= k_out_proj: 1536 blocks x 256 thr =======================
// Blocks 0..767: gated output(2) + intercept partial + ligand projection (1 row).
// Blocks 768..1535: protein projection (1 row) -> p2q packed. Runs right
// before k_energy so p1/p2q are L2-warm.
__global__ __launch_bounds__(256) void k_out_proj(
    const float* __restrict__ x, const float* __restrict__ hb,
    const float* __restrict__ att,
    const float* __restrict__ gW, const float* __restrict__ gb,
    const float* __restrict__ pW1, const float* __restrict__ pb1,
    const float* __restrict__ valid1, const float* __restrict__ h2g,
    float* __restrict__ xout, float* __restrict__ p1, float* __restrict__ p2q,
    float* __restrict__ wsi) {
  int blk = blockIdx.x, tid = threadIdx.x, c = tid & 127, jh = tid >> 7;
  if (blk >= 768) {
    // ---- protein projection, 1 row per block
    int rp = blk - 768;
    const float* xbase = h2g + rp * DD;   // block-uniform -> scalar path
    for (int o = tid; o < 640; o += 256) {
      int m = o >> 7, hc = o & 127;
      const float* Wcol = pW1 + (m * 256 + 128) * HH + hc;
      float a0 = 0.f, a1 = 0.f;
#pragma unroll 4
      for (int k = 0; k < DD; k += 2) {
        a0 += xbase[k] * Wcol[k * HH];
        a1 += xbase[k + 1] * Wcol[(k + 1) * HH];
      }
      p2q[(size_t)((m * 32 + (hc >> 2)) * 768 + rp) * 4 + (hc & 3)] = a0 + a1;
    }
    return;
  }
  int r = blk;
  int b = r / NN;
  __shared__ float ph[2][DD];
  __shared__ float redw[2];
  float xr = x[r * DD + c];        // prefetch
  float g1 = gW[c], g2 = gW[DD + c], gbv = gb[0];
  float vld = valid1[r];
  const float4* ar4 = (const float4*)(att + r * NN) + jh * 48;
  const float* hp = hb + (b * NN + jh * 192) * DD + c;
  float q0 = 0.f, q1 = 0.f, q2 = 0.f, q3 = 0.f;
#pragma unroll 4
  for (int j4 = 0; j4 < 48; ++j4) {
    float4 av = ar4[j4];
    const float* hj = hp + j4 * 4 * DD;
    q0 += av.x * hj[0];
    q1 += av.y * hj[DD];
    q2 += av.z * hj[2 * DD];
    q3 += av.w * hj[3 * DD];
  }
  ph[jh][c] = (q0 + q1) + (q2 + q3);
  __syncthreads();
  float hpr = 0.f;
  if (tid < 128) {
    hpr = fmaxf(ph[0][c] + ph[1][c], 0.f);
    float v = xr * g1 + hpr * g2;
#pragma unroll
    for (int off = 32; off > 0; off >>= 1) v += __shfl_down(v, off);
    if ((tid & 63) == 0) redw[tid >> 6] = v;
  }
  __syncthreads();
  if (tid < 128) {
    float coeff = sigmoidf_(redw[0] + redw[1] + gbv);
    float nv = coeff * xr + (1.f - coeff) * hpr;
    xout[r * DD + c] = nv;
    wsi[r * DD + c] = nv * vld;
  }
  __syncthreads();
  const float* xbase = xout + r * DD;   // block-uniform -> scalar path
  for (int o = tid; o < 640; o += 256) {
    int m = o >> 7, hc = o & 127;
    const float* Wcol = pW1 + (m * 256) * HH + hc;
    float a0 = 0.f, a1 = 0.f;
#pragma unroll 4
    for (int k = 0; k < DD; k += 2) {
      a0 += xbase[k] * Wcol[k * HH];
      a1 += xbase[k + 1] * Wcol[(k + 1) * HH];
    }
    p1[(r * 5 + m) * HH + hc] = a0 + a1 + pb1[m * HH + hc];
  }
}

// ================= k_energy: 385 blocks x 384 thr ==========================
// Blocks 0..383: TI=2 ligand rows, lane = j (full 384), full H per lane.
// HBM tail operands prefetched. Block 384: intercept MLP.
__global__ __launch_bounds__(384) void k_energy(
    const float* __restrict__ p1, const float* __restrict__ p2q,
    const float* __restrict__ W2, const float* __restrict__ b2,
    const float* __restrict__ dmv, const float* __restrict__ charge1,
    const float* __restrict__ charge2, const float* __restrict__ veps,
    const float* __restrict__ vsig, const float* __restrict__ valid1,
    const float* __restrict__ valid2, const float* __restrict__ nm1,
    const float* __restrict__ nm2, const float* __restrict__ vdw_coeff,
    const float* __restrict__ wsi, const float* __restrict__ iW1,
    const float* __restrict__ ib1, const float* __restrict__ iW2,
    const float* __restrict__ ib2, float* __restrict__ out) {
  int blk = blockIdx.x, tid = threadIdx.x;
  if (blk >= 384) {   // ---- intercept finisher
    if (tid < 256) {
      int bb = tid >> 7, cc = tid & 127;
      __shared__ float hsf[2][DD];
      __shared__ float redf[2][2];
      float a0 = 0.f, a1 = 0.f;
      for (int q = 0; q < 384; q += 2) {
        a0 += wsi[(bb * 384 + q) * DD + cc];
        a1 += wsi[(bb * 384 + q + 1) * DD + cc];
      }
      hsf[bb][cc] = a0 + a1;
      __syncthreads();
      float hid = ib1[cc];
#pragma unroll 4
      for (int k = 0; k < DD; ++k) hid += hsf[bb][k] * iW1[k * HH + cc];
      hid = fmaxf(hid, 0.f);
      float v = hid * iW2[cc];
#pragma unroll
      for (int off = 32; off > 0; off >>= 1) v += __shfl_down(v, off);
      if ((tid & 63) == 0) redf[bb][(tid >> 6) & 1] = v;
      __syncthreads();
      if (tid < 2) out[tid * 4 + 3] = redf[tid][0] + redf[tid][1] + ib2[0];
    }
    return;
  }
  int r0 = blk * 2;
  int b = r0 / NN;
  int j = tid;
  int col = b * NN + j;
  // ---- prefetch HBM tail operands (independent; in flight during MLP loop)
  int p0 = r0 * NN + j, pI = p0 + NN;
  float dx0 = dmv[3 * p0], dy0 = dmv[3 * p0 + 1], dz0 = dmv[3 * p0 + 2];
  float dx1 = dmv[3 * pI], dy1 = dmv[3 * pI + 1], dz1 = dmv[3 * pI + 2];
  float ve0 = veps[p0], ve1 = veps[pI];
  float vs0 = vsig[p0], vs1 = vsig[pI];
  float q2c = charge2[col], vv2 = valid2[col], n2 = nm2[col];
  float c1a = charge1[r0], c1b = charge1[r0 + 1];
  float vaa = valid1[r0], vab = valid1[r0 + 1];
  float naa = nm1[r0], nab = nm1[r0 + 1];
  float vc2 = vdw_coeff[0] * vdw_coeff[0];

  // ---- pair MLP (m-outer, full H, scalar-broadcast p1/W2, coalesced p2q)
  const float* q0 = p1 + (r0 + 0) * 640;   // uniform -> s_load
  const float* q1 = p1 + (r0 + 1) * 640;
  const float4* p2q4 = (const float4*)p2q;
  float acc0[5], acc1[5];
#pragma unroll
  for (int m = 0; m < 5; ++m) {
    const float4* pc = p2q4 + (size_t)(m * 32) * 768 + col;
    const float* x0m = q0 + m * HH;
    const float* x1m = q1 + m * HH;
    const float* w2m = W2 + m * HH;
    float a0 = 0.f, a1 = 0.f;
#pragma unroll 8
    for (int hq = 0; hq < 32; ++hq) {
      float4 pv = pc[(size_t)hq * 768];
      float w0 = w2m[4 * hq], w1 = w2m[4 * hq + 1];
      float w2v = w2m[4 * hq + 2], w3 = w2m[4 * hq + 3];
      a0 += fmaxf(x0m[4 * hq] + pv.x, 0.f) * w0 + fmaxf(x0m[4 * hq + 1] + pv.y, 0.f) * w1
          + fmaxf(x0m[4 * hq + 2] + pv.z, 0.f) * w2v + fmaxf(x0m[4 * hq + 3] + pv.w, 0.f) * w3;
      a1 += fmaxf(x1m[4 * hq] + pv.x, 0.f) * w0 + fmaxf(x1m[4 * hq + 1] + pv.y, 0.f) * w1
          + fmaxf(x1m[4 * hq + 2] + pv.z, 0.f) * w2v + fmaxf(x1m[4 * hq + 3] + pv.w, 0.f) * w3;
    }
    acc0[m] = a0 + b2[m]; acc1[m] = a1 + b2[m];
  }

  // ---- energies (operands already resident)
  float ec_sum = 0.f, ev_sum = 0.f;
  {
    float dm = sqrtf(dx0 * dx0 + dy0 * dy0 + dz0 * dz0 + 1e-10f);
    if (dm < 0.5f) dm = 1e10f;
    float cA = sigmoidf_(acc0[0]);
    float cN = sigmoidf_(acc0[1]) * 2.f + 1.f;
    float e_c = cA * c1a * q2c * __powf(1.f / dm, cN);
    e_c *= vaa * vv2;
    ec_sum += fminf(fmaxf(e_c, -100.f), 100.f);
    float vA = (sigmoidf_(acc0[2]) * 0.6f + 0.7f) * vc2 * ve0;
    float vB = tanhf_(acc0[3]) * 0.6f + 0.7f;
    float vN = sigmoidf_(acc0[4]) * 2.f + 5.f;
    float dm0 = vs0 * vB;
    if (dm0 < 1e-4f) dm0 = 1.f;
    float rr = __powf(dm0 / dm, vN);
    float e_v = vA * (rr * rr - 2.f * rr) * naa * n2;
    ev_sum += fminf(e_v, 100.f);
  }
  {
    float dm = sqrtf(dx1 * dx1 + dy1 * dy1 + dz1 * dz1 + 1e-10f);
    if (dm < 0.5f) dm = 1e10f;
    float cA = sigmoidf_(acc1[0]);
    float cN = sigmoidf_(acc1[1]) * 2.f + 1.f;
    float e_c = cA * c1b * q2c * __powf(1.f / dm, cN);
    e_c *= vab * vv2;
    ec_sum += fminf(fmaxf(e_c, -100.f), 100.f);
    float vA = (sigmoidf_(acc1[2]) * 0.6f + 0.7f) * vc2 * ve1;
    float vB = tanhf_(acc1[3]) * 0.6f + 0.7f;
    float vN = sigmoidf_(acc1[4]) * 2.f + 5.f;
    float dm0 = vs1 * vB;
    if (dm0 < 1e-4f) dm0 = 1.f;
    float rr = __powf(dm0 / dm, vN);
    float e_v = vA * (rr * rr - 2.f * rr) * nab * n2;
    ev_sum += fminf(e_v, 100.f);
  }
#pragma unroll
  for (int off = 32; off > 0; off >>= 1) {
    ec_sum += __shfl_down(ec_sum, off);
    ev_sum += __shfl_down(ev_sum, off);
  }
  __shared__ float rec[6], rev[6];
  if ((tid & 63) == 0) { rec[tid >> 6] = ec_sum; rev[tid >> 6] = ev_sum; }
  __syncthreads();
  if (tid == 0) {
    float a = 0.f, c = 0.f;
#pragma unroll
    for (int w = 0; w < 6; ++w) { a += rec[w]; c += rev[w]; }
    atomicAdd(&out[b * 4 + 0], a);
    atomicAdd(&out[b * 4 + 1], c);
  }
}

// ---------------------------------------------------------------- launch
extern "C" void kernel_launch(void* const* d_in, const int* in_sizes, int n_in,
                              void* d_out, int out_size, void* d_ws, size_t ws_size,
                              hipStream_t stream) {
  (void)in_sizes; (void)n_in; (void)out_size; (void)ws_size;
  const float* h1         = (const float*)d_in[0];
  const float* h2         = (const float*)d_in[1];
  const float* adj1       = (const float*)d_in[2];
  const float* dmv        = (const float*)d_in[3];
  const float* charge1    = (const float*)d_in[4];
  const float* charge2    = (const float*)d_in[5];
  const float* veps       = (const float*)d_in[6];
  const float* vsig       = (const float*)d_in[7];
  const float* delta_uff  = (const float*)d_in[8];
  const float* valid1     = (const float*)d_in[9];
  const float* valid2     = (const float*)d_in[10];
  const float* nm1        = (const float*)d_in[11];
  const float* nm2        = (const float*)d_in[12];
  const float* node_W     = (const float*)d_in[13];
  const float* gat_W      = (const float*)d_in[14];
  const float* gat_Wb     = (const float*)d_in[15];
  const float* gat_A      = (const float*)d_in[16];
  const float* gat_gW     = (const float*)d_in[17];
  const float* gat_gb     = (const float*)d_in[18];
  const float* pW1        = (const float*)d_in[19];
  const float* pb1        = (const float*)d_in[20];
  const float* pW2        = (const float*)d_in[21];
  const float* pb2        = (const float*)d_in[22];
  const float* vdw_coeff  = (const float*)d_in[23];
  const float* duff_coeff = (const float*)d_in[24];
  const float* iW1        = (const float*)d_in[25];
  const float* ib1        = (const float*)d_in[26];
  const float* iW2        = (const float*)d_in[27];
  const float* ib2        = (const float*)d_in[28];
  float* out = (float*)d_out;

  float* ws = (float*)d_ws;
  const int RN = 768 * DD;  // 98304
  float* h1gA = ws;               // x ping-pong A
  float* h1gB = h1gA + RN;        // x ping-pong B
  float* h2g  = h1gB + RN;
  float* hb0  = h2g  + RN;
  float* hA0  = hb0  + RN;
  float* hT0  = hA0  + RN;
  float* hAT0 = hT0  + RN;
  float* hb1  = hAT0 + RN;
  float* hA1  = hb1  + RN;
  float* hT1  = hA1  + RN;
  float* hAT1 = hT1  + RN;
  float* att  = hAT1 + RN;            // 2*384*384
  float* p1   = att + 2 * NN * NN;    // 768*640
  float* p2q  = p1 + 768 * 640;       // 768*640 packed
  float* wsi  = p2q + 768 * 640;      // 768*128

  const int DD2 = DD * DD;

  k_start<<<dim3(768), dim3(256), 0, stream>>>(
      h1, h2, node_W, gat_W, gat_Wb, gat_A, delta_uff, duff_coeff,
      h1gA, h2g, hb0, hA0, hT0, hAT0, out);

  // layer 0
  k_att<<<dim3(768), dim3(384), 0, stream>>>(hb0, hA0, hT0, hAT0, adj1, att);
  k_out_hhA<<<dim3(768), dim3(256), 0, stream>>>(
      h1gA, hb0, att, gat_gW + 0, gat_gb + 0,
      gat_W + DD2, gat_Wb + DD, gat_A + DD2,
      h1gB, hb1, hA1, hT1, hAT1);
  // layer 1
  k_att<<<dim3(768), dim3(384), 0, stream>>>(hb1, hA1, hT1, hAT1, adj1, att);
  k_out_hhA<<<dim3(768), dim3(256), 0, stream>>>(
      h1gB, hb1, att, gat_gW + 2 * DD, gat_gb + 1,
      gat_W + 2 * DD2, gat_Wb + 2 * DD, gat_A + 2 * DD2,
      h1gA, hb0, hA0, hT0, hAT0);
  // layer 2
  k_att<<<dim3(768), dim3(384), 0, stream>>>(hb0, hA0, hT0, hAT0, adj1, att);
  k_out_proj<<<dim3(1536), dim3(256), 0, stream>>>(
      h1gA, hb0, att, gat_gW + 4 * DD, gat_gb + 2,
      pW1, pb1, valid1, h2g, h1gB, p1, p2q, wsi);

  k_energy<<<dim3(385), dim3(384), 0, stream>>>(
      p1, p2q, pW2, pb2, dmv, charge1, charge2, veps, vsig,
      valid1, valid2, nm1, nm2, vdw_coeff, wsi, iW1, ib1, iW2, ib2, out);
}

// Round 12
// 266.975 us; speedup vs baseline: 1.2227x; 1.0686x over previous
//
#include <hip/hip_runtime.h>
#include <math.h>

#define NN 384
#define DD 128
#define HH 128

__device__ __forceinline__ float sigmoidf_(float x) { return 1.f / (1.f + __expf(-x)); }
__device__ __forceinline__ float tanhf_(float x)    { return 1.f - 2.f / (__expf(2.f * x) + 1.f); }

// ================= k_start: 768 blocks x 256 thr, 2 rows/block ============
__global__ __launch_bounds__(256) void k_start(
    const float* __restrict__ h1, const float* __restrict__ h2,
    const float* __restrict__ nW,
    const float* __restrict__ W, const float* __restrict__ Wb, const float* __restrict__ A,
    const float* __restrict__ delta_uff, const float* __restrict__ duff,
    float* __restrict__ h1g, float* __restrict__ h2g,
    float* __restrict__ hb, float* __restrict__ hAb,
    float* __restrict__ hT, float* __restrict__ hAT,
    float* __restrict__ out) {
  int blk = blockIdx.x, tid = threadIdx.x, c = tid & 127, g = tid >> 7;  // g in {0,1}
  if (blk == 0 && tid < 8) {
    int bb = tid >> 2, cc = tid & 3;
    out[tid] = (cc == 2) ? duff[0] * duff[0] * delta_uff[bb] : 0.f;
  }
  if (blk < 384) {
    int r = blk * 2 + g;
    const float* xr = h1 + r * 54;
    float acc = 0.f;
#pragma unroll 6
    for (int k = 0; k < 54; ++k) acc += xr[k] * nW[k * DD + c];
    h1g[r * DD + c] = acc;
    __syncthreads();
    const float4* xr4 = (const float4*)(h1g + r * DD);
    float a0 = 0.f, a1 = 0.f;
#pragma unroll 4
    for (int k4 = 0; k4 < DD / 4; ++k4) {
      float4 xv = xr4[k4]; int k = 4 * k4;
      a0 += xv.x * W[k * DD + c] + xv.z * W[(k + 2) * DD + c];
      a1 += xv.y * W[(k + 1) * DD + c] + xv.w * W[(k + 3) * DD + c];
    }
    float hv = a0 + a1 + Wb[c];
    hb[r * DD + c] = hv; hT[c * 768 + r] = hv;
    __syncthreads();
    const float4* hr4 = (const float4*)(hb + r * DD);
    a0 = 0.f; a1 = 0.f;
#pragma unroll 4
    for (int k4 = 0; k4 < DD / 4; ++k4) {
      float4 xv = hr4[k4]; int k = 4 * k4;
      a0 += xv.x * A[k * DD + c] + xv.z * A[(k + 2) * DD + c];
      a1 += xv.y * A[(k + 1) * DD + c] + xv.w * A[(k + 3) * DD + c];
    }
    float av = a0 + a1;
    hAb[r * DD + c] = av; hAT[c * 768 + r] = av;
  } else {
    int r = (blk - 384) * 2 + g;
    const float* xr = h2 + r * 54;
    float acc = 0.f;
#pragma unroll 6
    for (int k = 0; k < 54; ++k) acc += xr[k] * nW[k * DD + c];
    h2g[r * DD + c] = acc;
  }
}

// ================= k_att: 384 blocks x 384 thr, 2 columns/block ============
// Each lane loads hT/hAT once per cc and feeds BOTH columns (4 FMA / 2 loads).
// k-rows of h/hA are uniform (s_load). Stores att row-major as float2.
__global__ __launch_bounds__(384) void k_att(
    const float* __restrict__ hb, const float* __restrict__ hAb,
    const float* __restrict__ hT, const float* __restrict__ hAT,
    const float* __restrict__ adj, float* __restrict__ att) {
  int blk = blockIdx.x;
  int b = blk / 192;
  int kk = (blk - b * 192) * 2;
  int col0 = b * NN + kk, col1 = col0 + 1;
  int tid = threadIdx.x;         // j
  float a0 = adj[col0 * NN + tid];   // adj symmetric; prefetch (HBM)
  float a1 = adj[col1 * NN + tid];
  const float* h0r = hb  + col0 * DD;   // uniform streams (s_load)
  const float* g0r = hAb + col0 * DD;
  const float* h1r = hb  + col1 * DD;
  const float* g1r = hAb + col1 * DD;
  const float* hTb  = hT  + b * NN + tid;
  const float* hATb = hAT + b * NN + tid;
  float e0a = 0.f, e0b = 0.f, e1a = 0.f, e1b = 0.f;
#pragma unroll 4
  for (int cc = 0; cc < DD; cc += 2) {
    float tv0 = hTb[cc * 768], av0 = hATb[cc * 768];
    float tv1 = hTb[(cc + 1) * 768], av1 = hATb[(cc + 1) * 768];
    e0a += av0 * h0r[cc] + tv0 * g0r[cc];
    e0b += av1 * h0r[cc + 1] + tv1 * g0r[cc + 1];
    e1a += av0 * h1r[cc] + tv0 * g1r[cc];
    e1b += av1 * h1r[cc + 1] + tv1 * g1r[cc + 1];
  }
  float e0 = e0a + e0b, e1 = e1a + e1b;
  __shared__ float red[2][6];
  float l0 = (a0 > 0.f) ? e0 : -3e38f;
  float l1 = (a1 > 0.f) ? e1 : -3e38f;
#pragma unroll
  for (int off = 32; off > 0; off >>= 1) {
    l0 = fmaxf(l0, __shfl_down(l0, off));
    l1 = fmaxf(l1, __shfl_down(l1, off));
  }
  int w = tid >> 6;
  if ((tid & 63) == 0) { red[0][w] = l0; red[1][w] = l1; }
  __syncthreads();
  float m0 = red[0][0], m1 = red[1][0];
#pragma unroll
  for (int q = 1; q < 6; ++q) { m0 = fmaxf(m0, red[0][q]); m1 = fmaxf(m1, red[1][q]); }
  float v0 = (a0 > 0.f) ? __expf(e0 - m0) : 0.f;
  float v1 = (a1 > 0.f) ? __expf(e1 - m1) : 0.f;
  float s0 = v0, s1 = v1;
#pragma unroll
  for (int off = 32; off > 0; off >>= 1) {
    s0 += __shfl_down(s0, off);
    s1 += __shfl_down(s1, off);
  }
  __syncthreads();
  if ((tid & 63) == 0) { red[0][w] = s0; red[1][w] = s1; }
  __syncthreads();
  float d0 = 0.f, d1 = 0.f;
#pragma unroll
  for (int q = 0; q < 6; ++q) { d0 += red[0][q]; d1 += red[1][q]; }
  float2 wv = make_float2(v0 * a0 / d0, v1 * a1 / d1);
  *(float2*)(att + (b * NN + tid) * NN + kk) = wv;   // row-major 8B store
}

// ================= k_out_hhA: 384 blocks x 256 thr, 2 rows/block ===========
// h loads + W/A streams each feed BOTH rows' accumulators (register reuse).
__global__ __launch_bounds__(256) void k_out_hhA(
    const float* __restrict__ x, const float* __restrict__ hb,
    const float* __restrict__ att,
    const float* __restrict__ gW, const float* __restrict__ gb,
    const float* __restrict__ Wn, const float* __restrict__ Wbn,
    const float* __restrict__ An,
    float* __restrict__ xout,
    float* __restrict__ hbn, float* __restrict__ hAbn,
    float* __restrict__ hTn, float* __restrict__ hATn) {
  int r0 = blockIdx.x * 2;       // rows r0, r0+1 (same batch)
  int b = r0 / NN;
  int tid = threadIdx.x, c = tid & 127, jh = tid >> 7;
  __shared__ float ph[2][2][DD];   // [jh][row][c]
  __shared__ float redw[2][2];     // [row][wave-pair]
  float xr0 = x[(r0 + 0) * DD + c];   // prefetch
  float xr1 = x[(r0 + 1) * DD + c];
  float g1 = gW[c], g2 = gW[DD + c], gbv = gb[0];
  // ---- att@h: j-half per jh group, h loads shared across 2 rows
  const float4* a0p = (const float4*)(att + (r0 + 0) * NN) + jh * 48;  // uniform
  const float4* a1p = (const float4*)(att + (r0 + 1) * NN) + jh * 48;
  const float* hp = hb + (b * NN + jh * 192) * DD + c;
  float q00 = 0.f, q01 = 0.f, q10 = 0.f, q11 = 0.f;
#pragma unroll 4
  for (int j4 = 0; j4 < 48; ++j4) {
    float4 av0 = a0p[j4], av1 = a1p[j4];
    const float* hj = hp + j4 * 4 * DD;
    float h0 = hj[0], h1v = hj[DD], h2v = hj[2 * DD], h3 = hj[3 * DD];
    q00 += av0.x * h0 + av0.y * h1v;
    q01 += av0.z * h2v + av0.w * h3;
    q10 += av1.x * h0 + av1.y * h1v;
    q11 += av1.z * h2v + av1.w * h3;
  }
  ph[jh][0][c] = q00 + q01;
  ph[jh][1][c] = q10 + q11;
  __syncthreads();
  float hpr0 = 0.f, hpr1 = 0.f;
  if (tid < 128) {
    hpr0 = fmaxf(ph[0][0][c] + ph[1][0][c], 0.f);
    hpr1 = fmaxf(ph[0][1][c] + ph[1][1][c], 0.f);
    float v0 = xr0 * g1 + hpr0 * g2;
    float v1 = xr1 * g1 + hpr1 * g2;
#pragma unroll
    for (int off = 32; off > 0; off >>= 1) {
      v0 += __shfl_down(v0, off);
      v1 += __shfl_down(v1, off);
    }
    if ((tid & 63) == 0) { redw[0][tid >> 6] = v0; redw[1][tid >> 6] = v1; }
  }
  __syncthreads();
  if (tid < 128) {
    float c0 = sigmoidf_(redw[0][0] + redw[0][1] + gbv);
    float c1 = sigmoidf_(redw[1][0] + redw[1][1] + gbv);
    xout[(r0 + 0) * DD + c] = c0 * xr0 + (1.f - c0) * hpr0;
    xout[(r0 + 1) * DD + c] = c1 * xr1 + (1.f - c1) * hpr1;
  }
  __syncthreads();
  // ---- h(l+1): W stream shared across 2 rows; k-half per jh
  const float* xb0 = xout + (r0 + 0) * DD + jh * 64;   // uniform
  const float* xb1 = xout + (r0 + 1) * DD + jh * 64;
  const float* Wp = Wn + (jh * 64) * DD + c;
  float a00 = 0.f, a01 = 0.f, a10 = 0.f, a11 = 0.f;
#pragma unroll 4
  for (int k = 0; k < 64; k += 2) {
    float w0 = Wp[k * DD], w1 = Wp[(k + 1) * DD];
    a00 += xb0[k] * w0; a01 += xb0[k + 1] * w1;
    a10 += xb1[k] * w0; a11 += xb1[k + 1] * w1;
  }
  ph[jh][0][c] = a00 + a01;
  ph[jh][1][c] = a10 + a11;
  __syncthreads();
  if (tid < 128) {
    float wb = Wbn[c];
    float hv0 = ph[0][0][c] + ph[1][0][c] + wb;
    float hv1 = ph[0][1][c] + ph[1][1][c] + wb;
    hbn[(r0 + 0) * DD + c] = hv0; hTn[c * 768 + r0 + 0] = hv0;
    hbn[(r0 + 1) * DD + c] = hv1; hTn[c * 768 + r0 + 1] = hv1;
  }
  __syncthreads();
  // ---- hA(l+1): A stream shared across 2 rows
  const float* hb0p = hbn + (r0 + 0) * DD + jh * 64;   // uniform
  const float* hb1p = hbn + (r0 + 1) * DD + jh * 64;
  const float* Ap = An + (jh * 64) * DD + c;
  a00 = 0.f; a01 = 0.f; a10 = 0.f; a11 = 0.f;
#pragma unroll 4
  for (int k = 0; k < 64; k += 2) {
    float w0 = Ap[k * DD], w1 = Ap[(k + 1) * DD];
    a00 += hb0p[k] * w0; a01 += hb0p[k + 1] * w1;
    a10 += hb1p[k] * w0; a11 += hb1p[k + 1] * w1;
  }
  ph[jh][0][c] = a00 + a01;
  ph[jh][1][c] = a10 + a11;
  __syncthreads();
  if (tid < 128) {
    float av0 = ph[0][0][c] + ph[1][0][c];
    float av1 = ph[0][1][c] + ph[1][1][c];
    hAbn[(r0 + 0) * DD + c] = av0; hATn[c * 768 + r0 + 0] = av0;
    hAbn[(r0 + 1) * DD + c] = av1; hATn[c * 768 + r0 + 1] = av1;
  }
}

// ================= k_out_proj: 768 blocks x 256 thr, 2 rows/block ==========
// Blocks 0..383: 2 ligand rows (gated output(2) + intercept partial + proj).
// Blocks 384..767: 2 protein rows (proj -> p2q). Weight stream shared per pair.
__global__ __launch_bounds__(256) void k_out_proj(
    const float* __restrict__ x, const float* __restrict__ hb,
    const float* __restrict__ att,
    const float* __restrict__ gW, const float* __restrict__ gb,
    const float* __restrict__ pW1, const float* __restrict__ pb1,
    const float* __restrict__ valid1, const float* __restrict__ h2g,
    float* __restrict__ xout, float* __restrict__ p1, float* __restrict__ p2q,
    float* __restrict__ wsi) {
  int blk = blockIdx.x, tid = threadIdx.x, c = tid & 127, jh = tid >> 7;
  if (blk >= 384) {
    // ---- protein projection, 2 rows per block
    int rp = (blk - 384) * 2;
    const float* xb0 = h2g + (rp + 0) * DD;   // uniform -> scalar path
    const float* xb1 = h2g + (rp + 1) * DD;
    for (int o = tid; o < 640; o += 256) {
      int m = o >> 7, hc = o & 127;
      const float* Wcol = pW1 + (m * 256 + 128) * HH + hc;
      float a00 = 0.f, a01 = 0.f, a10 = 0.f, a11 = 0.f;
#pragma unroll 4
      for (int k = 0; k < DD; k += 2) {
        float w0 = Wcol[k * HH], w1 = Wcol[(k + 1) * HH];
        a00 += xb0[k] * w0; a01 += xb0[k + 1] * w1;
        a10 += xb1[k] * w0; a11 += xb1[k + 1] * w1;
      }
      float* dst = p2q + (size_t)((m * 32 + (hc >> 2)) * 768 + rp) * 4 + (hc & 3);
      dst[0] = a00 + a01;
      dst[4] = a10 + a11;
    }
    return;
  }
  int r0 = blk * 2;
  int b = r0 / NN;
  __shared__ float ph[2][2][DD];
  __shared__ float redw[2][2];
  float xr0 = x[(r0 + 0) * DD + c];
  float xr1 = x[(r0 + 1) * DD + c];
  float g1 = gW[c], g2 = gW[DD + c], gbv = gb[0];
  float vld0 = valid1[r0], vld1 = valid1[r0 + 1];
  const float4* a0p = (const float4*)(att + (r0 + 0) * NN) + jh * 48;
  const float4* a1p = (const float4*)(att + (r0 + 1) * NN) + jh * 48;
  const float* hp = hb + (b * NN + jh * 192) * DD + c;
  float q00 = 0.f, q01 = 0.f, q10 = 0.f, q11 = 0.f;
#pragma unroll 4
  for (int j4 = 0; j4 < 48; ++j4) {
    float4 av0 = a0p[j4], av1 = a1p[j4];
    const float* hj = hp + j4 * 4 * DD;
    float h0 = hj[0], h1v = hj[DD], h2v = hj[2 * DD], h3 = hj[3 * DD];
    q00 += av0.x * h0 + av0.y * h1v;
    q01 += av0.z * h2v + av0.w * h3;
    q10 += av1.x * h0 + av1.y * h1v;
    q11 += av1.z * h2v + av1.w * h3;
  }
  ph[jh][0][c] = q00 + q01;
  ph[jh][1][c] = q10 + q11;
  __syncthreads();
  float hpr0 = 0.f, hpr1 = 0.f;
  if (tid < 128) {
    hpr0 = fmaxf(ph[0][0][c] + ph[1][0][c], 0.f);
    hpr1 = fmaxf(ph[0][1][c] + ph[1][1][c], 0.f);
    float v0 = xr0 * g1 + hpr0 * g2;
    float v1 = xr1 * g1 + hpr1 * g2;
#pragma unroll
    for (int off = 32; off > 0; off >>= 1) {
      v0 += __shfl_down(v0, off);
      v1 += __shfl_down(v1, off);
    }
    if ((tid & 63) == 0) { redw[0][tid >> 6] = v0; redw[1][tid >> 6] = v1; }
  }
  __syncthreads();
  if (tid < 128) {
    float c0 = sigmoidf_(redw[0][0] + redw[0][1] + gbv);
    float c1 = sigmoidf_(redw[1][0] + redw[1][1] + gbv);
    float nv0 = c0 * xr0 + (1.f - c0) * hpr0;
    float nv1 = c1 * xr1 + (1.f - c1) * hpr1;
    xout[(r0 + 0) * DD + c] = nv0;
    xout[(r0 + 1) * DD + c] = nv1;
    wsi[(r0 + 0) * DD + c] = nv0 * vld0;
    wsi[(r0 + 1) * DD + c] = nv1 * vld1;
  }
  __syncthreads();
  // ---- ligand projection for 2 rows, shared weight stream
  const float* xb0 = xout + (r0 + 0) * DD;   // uniform -> scalar path
  const float* xb1 = xout + (r0 + 1) * DD;
  for (int o = tid; o < 640; o += 256) {
    int m = o >> 7, hc = o & 127;
    const float* Wcol = pW1 + (m * 256) * HH + hc;
    float a00 = 0.f, a01 = 0.f, a10 = 0.f, a11 = 0.f;
#pragma unroll 4
    for (int k = 0; k < DD; k += 2) {
      float w0 = Wcol[k * HH], w1 = Wcol[(k + 1) * HH];
      a00 += xb0[k] * w0; a01 += xb0[k + 1] * w1;
      a10 += xb1[k] * w0; a11 += xb1[k + 1] * w1;
    }
    float bias = pb1[m * HH + hc];
    p1[((r0 + 0) * 5 + m) * HH + hc] = a00 + a01 + bias;
    p1[((r0 + 1) * 5 + m) * HH + hc] = a10 + a11 + bias;
  }
}

// ================= k_energy: 385 blocks x 384 thr ==========================
__global__ __launch_bounds__(384) void k_energy(
    const float* __restrict__ p1, const float* __restrict__ p2q,
    const float* __restrict__ W2, const float* __restrict__ b2,
    const float* __restrict__ dmv, const float* __restrict__ charge1,
    const float* __restrict__ charge2, const float* __restrict__ veps,
    const float* __restrict__ vsig, const float* __restrict__ valid1,
    const float* __restrict__ valid2, const float* __restrict__ nm1,
    const float* __restrict__ nm2, const float* __restrict__ vdw_coeff,
    const float* __restrict__ wsi, const float* __restrict__ iW1,
    const float* __restrict__ ib1, const float* __restrict__ iW2,
    const float* __restrict__ ib2, float* __restrict__ out) {
  int blk = blockIdx.x, tid = threadIdx.x;
  if (blk >= 384) {   // ---- intercept finisher
    if (tid < 256) {
      int bb = tid >> 7, cc = tid & 127;
      __shared__ float hsf[2][DD];
      __shared__ float redf[2][2];
      float a0 = 0.f, a1 = 0.f;
      for (int q = 0; q < 384; q += 2) {
        a0 += wsi[(bb * 384 + q) * DD + cc];
        a1 += wsi[(bb * 384 + q + 1) * DD + cc];
      }
      hsf[bb][cc] = a0 + a1;
      __syncthreads();
      float hid = ib1[cc];
#pragma unroll 4
      for (int k = 0; k < DD; ++k) hid += hsf[bb][k] * iW1[k * HH + cc];
      hid = fmaxf(hid, 0.f);
      float v = hid * iW2[cc];
#pragma unroll
      for (int off = 32; off > 0; off >>= 1) v += __shfl_down(v, off);
      if ((tid & 63) == 0) redf[bb][(tid >> 6) & 1] = v;
      __syncthreads();
      if (tid < 2) out[tid * 4 + 3] = redf[tid][0] + redf[tid][1] + ib2[0];
    }
    return;
  }
  int r0 = blk * 2;
  int b = r0 / NN;
  int j = tid;
  int col = b * NN + j;
  // ---- prefetch HBM tail operands
  int p0 = r0 * NN + j, pI = p0 + NN;
  float dx0 = dmv[3 * p0], dy0 = dmv[3 * p0 + 1], dz0 = dmv[3 * p0 + 2];
  float dx1 = dmv[3 * pI], dy1 = dmv[3 * pI + 1], dz1 = dmv[3 * pI + 2];
  float ve0 = veps[p0], ve1 = veps[pI];
  float vs0 = vsig[p0], vs1 = vsig[pI];
  float q2c = charge2[col], vv2 = valid2[col], n2 = nm2[col];
  float c1a = charge1[r0], c1b = charge1[r0 + 1];
  float vaa = valid1[r0], vab = valid1[r0 + 1];
  float naa = nm1[r0], nab = nm1[r0 + 1];
  float vc2 = vdw_coeff[0] * vdw_coeff[0];

  const float* q0 = p1 + (r0 + 0) * 640;   // uniform -> s_load
  const float* q1 = p1 + (r0 + 1) * 640;
  const float4* p2q4 = (const float4*)p2q;
  float acc0[5], acc1[5];
#pragma unroll
  for (int m = 0; m < 5; ++m) {
    const float4* pc = p2q4 + (size_t)(m * 32) * 768 + col;
    const float* x0m = q0 + m * HH;
    const float* x1m = q1 + m * HH;
    const float* w2m = W2 + m * HH;
    float a0 = 0.f, a1 = 0.f;
#pragma unroll 8
    for (int hq = 0; hq < 32; ++hq) {
      float4 pv = pc[(size_t)hq * 768];
      float w0 = w2m[4 * hq], w1 = w2m[4 * hq + 1];
      float w2v = w2m[4 * hq + 2], w3 = w2m[4 * hq + 3];
      a0 += fmaxf(x0m[4 * hq] + pv.x, 0.f) * w0 + fmaxf(x0m[4 * hq + 1] + pv.y, 0.f) * w1
          + fmaxf(x0m[4 * hq + 2] + pv.z, 0.f) * w2v + fmaxf(x0m[4 * hq + 3] + pv.w, 0.f) * w3;
      a1 += fmaxf(x1m[4 * hq] + pv.x, 0.f) * w0 + fmaxf(x1m[4 * hq + 1] + pv.y, 0.f) * w1
          + fmaxf(x1m[4 * hq + 2] + pv.z, 0.f) * w2v + fmaxf(x1m[4 * hq + 3] + pv.w, 0.f) * w3;
    }
    acc0[m] = a0 + b2[m]; acc1[m] = a1 + b2[m];
  }

  float ec_sum = 0.f, ev_sum = 0.f;
  {
    float dm = sqrtf(dx0 * dx0 + dy0 * dy0 + dz0 * dz0 + 1e-10f);
    if (dm < 0.5f) dm = 1e10f;
    float cA = sigmoidf_(acc0[0]);
    float cN = sigmoidf_(acc0[1]) * 2.f + 1.f;
    float e_c = cA * c1a * q2c * __powf(1.f / dm, cN);
    e_c *= vaa * vv2;
    ec_sum += fminf(fmaxf(e_c, -100.f), 100.f);
    float vA = (sigmoidf_(acc0[2]) * 0.6f + 0.7f) * vc2 * ve0;
    float vB = tanhf_(acc0[3]) * 0.6f + 0.7f;
    float vN = sigmoidf_(acc0[4]) * 2.f + 5.f;
    float dm0 = vs0 * vB;
    if (dm0 < 1e-4f) dm0 = 1.f;
    float rr = __powf(dm0 / dm, vN);
    float e_v = vA * (rr * rr - 2.f * rr) * naa * n2;
    ev_sum += fminf(e_v, 100.f);
  }
  {
    float dm = sqrtf(dx1 * dx1 + dy1 * dy1 + dz1 * dz1 + 1e-10f);
    if (dm < 0.5f) dm = 1e10f;
    float cA = sigmoidf_(acc1[0]);
    float cN = sigmoidf_(acc1[1]) * 2.f + 1.f;
    float e_c = cA * c1b * q2c * __powf(1.f / dm, cN);
    e_c *= vab * vv2;
    ec_sum += fminf(fmaxf(e_c, -100.f), 100.f);
    float vA = (sigmoidf_(acc1[2]) * 0.6f + 0.7f) * vc2 * ve1;
    float vB = tanhf_(acc1[3]) * 0.6f + 0.7f;
    float vN = sigmoidf_(acc1[4]) * 2.f + 5.f;
    float dm0 = vs1 * vB;
    if (dm0 < 1e-4f) dm0 = 1.f;
    float rr = __powf(dm0 / dm, vN);
    float e_v = vA * (rr * rr - 2.f * rr) * nab * n2;
    ev_sum += fminf(e_v, 100.f);
  }
#pragma unroll
  for (int off = 32; off > 0; off >>= 1) {
    ec_sum += __shfl_down(ec_sum, off);
    ev_sum += __shfl_down(ev_sum, off);
  }
  __shared__ float rec[6], rev[6];
  if ((tid & 63) == 0) { rec[tid >> 6] = ec_sum; rev[tid >> 6] = ev_sum; }
  __syncthreads();
  if (tid == 0) {
    float a = 0.f, c = 0.f;
#pragma unroll
    for (int w = 0; w < 6; ++w) { a += rec[w]; c += rev[w]; }
    atomicAdd(&out[b * 4 + 0], a);
    atomicAdd(&out[b * 4 + 1], c);
  }
}

// ---------------------------------------------------------------- launch
extern "C" void kernel_launch(void* const* d_in, const int* in_sizes, int n_in,
                              void* d_out, int out_size, void* d_ws, size_t ws_size,
                              hipStream_t stream) {
  (void)in_sizes; (void)n_in; (void)out_size; (void)ws_size;
  const float* h1         = (const float*)d_in[0];
  const float* h2         = (const float*)d_in[1];
  const float* adj1       = (const float*)d_in[2];
  const float* dmv        = (const float*)d_in[3];
  const float* charge1    = (const float*)d_in[4];
  const float* charge2    = (const float*)d_in[5];
  const float* veps       = (const float*)d_in[6];
  const float* vsig       = (const float*)d_in[7];
  const float* delta_uff  = (const float*)d_in[8];
  const float* valid1     = (const float*)d_in[9];
  const float* valid2     = (const float*)d_in[10];
  const float* nm1        = (const float*)d_in[11];
  const float* nm2        = (const float*)d_in[12];
  const float* node_W     = (const float*)d_in[13];
  const float* gat_W      = (const float*)d_in[14];
  const float* gat_Wb     = (const float*)d_in[15];
  const float* gat_A      = (const float*)d_in[16];
  const float* gat_gW     = (const float*)d_in[17];
  const float* gat_gb     = (const float*)d_in[18];
  const float* pW1        = (const float*)d_in[19];
  const float* pb1        = (const float*)d_in[20];
  const float* pW2        = (const float*)d_in[21];
  const float* pb2        = (const float*)d_in[22];
  const float* vdw_coeff  = (const float*)d_in[23];
  const float* duff_coeff = (const float*)d_in[24];
  const float* iW1        = (const float*)d_in[25];
  const float* ib1        = (const float*)d_in[26];
  const float* iW2        = (const float*)d_in[27];
  const float* ib2        = (const float*)d_in[28];
  float* out = (float*)d_out;

  float* ws = (float*)d_ws;
  const int RN = 768 * DD;  // 98304
  float* h1gA = ws;               // x ping-pong A
  float* h1gB = h1gA + RN;        // x ping-pong B
  float* h2g  = h1gB + RN;
  float* hb0  = h2g  + RN;
  float* hA0  = hb0  + RN;
  float* hT0  = hA0  + RN;
  float* hAT0 = hT0  + RN;
  float* hb1  = hAT0 + RN;
  float* hA1  = hb1  + RN;
  float* hT1  = hA1  + RN;
  float* hAT1 = hT1  + RN;
  float* att  = hAT1 + RN;            // 2*384*384
  float* p1   = att + 2 * NN * NN;    // 768*640
  float* p2q  = p1 + 768 * 640;       // 768*640 packed
  float* wsi  = p2q + 768 * 640;      // 768*128

  const int DD2 = DD * DD;

  k_start<<<dim3(768), dim3(256), 0, stream>>>(
      h1, h2, node_W, gat_W, gat_Wb, gat_A, delta_uff, duff_coeff,
      h1gA, h2g, hb0, hA0, hT0, hAT0, out);

  // layer 0
  k_att<<<dim3(384), dim3(384), 0, stream>>>(hb0, hA0, hT0, hAT0, adj1, att);
  k_out_hhA<<<dim3(384), dim3(256), 0, stream>>>(
      h1gA, hb0, att, gat_gW + 0, gat_gb + 0,
      gat_W + DD2, gat_Wb + DD, gat_A + DD2,
      h1gB, hb1, hA1, hT1, hAT1);
  // layer 1
  k_att<<<dim3(384), dim3(384), 0, stream>>>(hb1, hA1, hT1, hAT1, adj1, att);
  k_out_hhA<<<dim3(384), dim3(256), 0, stream>>>(
      h1gB, hb1, att, gat_gW + 2 * DD, gat_gb + 1,
      gat_W + 2 * DD2, gat_Wb + 2 * DD, gat_A + 2 * DD2,
      h1gA, hb0, hA0, hT0, hAT0);
  // layer 2
  k_att<<<dim3(384), dim3(384), 0, stream>>>(hb0, hA0, hT0, hAT0, adj1, att);
  k_out_proj<<<dim3(768), dim3(256), 0, stream>>>(
      h1gA, hb0, att, gat_gW + 4 * DD, gat_gb + 2,
      pW1, pb1, valid1, h2g, h1gB, p1, p2q, wsi);

  k_energy<<<dim3(385), dim3(384), 0, stream>>>(
      p1, p2q, pW2, pb2, dmv, charge1, charge2, veps, vsig,
      valid1, valid2, nm1, nm2, vdw_coeff, wsi, iW1, ib1, iW2, ib2, out);
}

// Round 13
// 264.774 us; speedup vs baseline: 1.2328x; 1.0083x over previous
//
#include <hip/hip_runtime.h>
#include <math.h>

#define NN 384
#define DD 128
#define HH 128

__device__ __forceinline__ float sigmoidf_(float x) { return 1.f / (1.f + __expf(-x)); }
__device__ __forceinline__ float tanhf_(float x)    { return 1.f - 2.f / (__expf(2.f * x) + 1.f); }

// hTq/hATq packed layout: float4 group g=(c>>2), addr = (g*768 + row)*4 + (c&3)

// ================= k_start: 768 blocks x 256 thr, 2 rows/block ============
__global__ __launch_bounds__(256) void k_start(
    const float* __restrict__ h1, const float* __restrict__ h2,
    const float* __restrict__ nW,
    const float* __restrict__ W, const float* __restrict__ Wb, const float* __restrict__ A,
    const float* __restrict__ delta_uff, const float* __restrict__ duff,
    float* __restrict__ h1g, float* __restrict__ h2g,
    float* __restrict__ hb, float* __restrict__ hAb,
    float* __restrict__ hTq, float* __restrict__ hATq,
    float* __restrict__ out) {
  int blk = blockIdx.x, tid = threadIdx.x, c = tid & 127, g = tid >> 7;  // g in {0,1}
  if (blk == 0 && tid < 8) {
    int bb = tid >> 2, cc = tid & 3;
    out[tid] = (cc == 2) ? duff[0] * duff[0] * delta_uff[bb] : 0.f;
  }
  if (blk < 384) {
    int r = blk * 2 + g;
    const float* xr = h1 + r * 54;
    float acc = 0.f;
#pragma unroll 6
    for (int k = 0; k < 54; ++k) acc += xr[k] * nW[k * DD + c];
    h1g[r * DD + c] = acc;
    __syncthreads();
    const float4* xr4 = (const float4*)(h1g + r * DD);
    float a0 = 0.f, a1 = 0.f;
#pragma unroll 4
    for (int k4 = 0; k4 < DD / 4; ++k4) {
      float4 xv = xr4[k4]; int k = 4 * k4;
      a0 += xv.x * W[k * DD + c] + xv.z * W[(k + 2) * DD + c];
      a1 += xv.y * W[(k + 1) * DD + c] + xv.w * W[(k + 3) * DD + c];
    }
    float hv = a0 + a1 + Wb[c];
    hb[r * DD + c] = hv;
    hTq[(size_t)((c >> 2) * 768 + r) * 4 + (c & 3)] = hv;
    __syncthreads();
    const float4* hr4 = (const float4*)(hb + r * DD);
    a0 = 0.f; a1 = 0.f;
#pragma unroll 4
    for (int k4 = 0; k4 < DD / 4; ++k4) {
      float4 xv = hr4[k4]; int k = 4 * k4;
      a0 += xv.x * A[k * DD + c] + xv.z * A[(k + 2) * DD + c];
      a1 += xv.y * A[(k + 1) * DD + c] + xv.w * A[(k + 3) * DD + c];
    }
    float av = a0 + a1;
    hAb[r * DD + c] = av;
    hATq[(size_t)((c >> 2) * 768 + r) * 4 + (c & 3)] = av;
  } else {
    int r = (blk - 384) * 2 + g;
    const float* xr = h2 + r * 54;
    float acc = 0.f;
#pragma unroll 6
    for (int k = 0; k < 54; ++k) acc += xr[k] * nW[k * DD + c];
    h2g[r * DD + c] = acc;
  }
}

// ================= k_att: 384 blocks x 384 thr, 2 columns/block ============
// hTq/hATq float4 loads (128/lane, was 512 dwords); k-rows uniform (s_load).
__global__ __launch_bounds__(384) void k_att(
    const float* __restrict__ hb, const float* __restrict__ hAb,
    const float* __restrict__ hTq, const float* __restrict__ hATq,
    const float* __restrict__ adj, float* __restrict__ att) {
  int blk = blockIdx.x;
  int b = blk / 192;
  int kk = (blk - b * 192) * 2;
  int col0 = b * NN + kk, col1 = col0 + 1;
  int tid = threadIdx.x;         // j
  float a0 = adj[col0 * NN + tid];   // adj symmetric; prefetch (HBM)
  float a1 = adj[col1 * NN + tid];
  const float* h0r = hb  + col0 * DD;   // uniform streams (s_load)
  const float* g0r = hAb + col0 * DD;
  const float* h1r = hb  + col1 * DD;
  const float* g1r = hAb + col1 * DD;
  const float4* hT4  = (const float4*)hTq  + b * NN + tid;
  const float4* hAT4 = (const float4*)hATq + b * NN + tid;
  float e0a = 0.f, e0b = 0.f, e1a = 0.f, e1b = 0.f;
#pragma unroll 4
  for (int c4 = 0; c4 < DD / 4; ++c4) {
    float4 tv = hT4[(size_t)c4 * 768];
    float4 av = hAT4[(size_t)c4 * 768];
    int cc = 4 * c4;
    e0a += av.x * h0r[cc] + av.y * h0r[cc + 1] + tv.x * g0r[cc] + tv.y * g0r[cc + 1];
    e0b += av.z * h0r[cc + 2] + av.w * h0r[cc + 3] + tv.z * g0r[cc + 2] + tv.w * g0r[cc + 3];
    e1a += av.x * h1r[cc] + av.y * h1r[cc + 1] + tv.x * g1r[cc] + tv.y * g1r[cc + 1];
    e1b += av.z * h1r[cc + 2] + av.w * h1r[cc + 3] + tv.z * g1r[cc + 2] + tv.w * g1r[cc + 3];
  }
  float e0 = e0a + e0b, e1 = e1a + e1b;
  __shared__ float red[2][6];
  float l0 = (a0 > 0.f) ? e0 : -3e38f;
  float l1 = (a1 > 0.f) ? e1 : -3e38f;
#pragma unroll
  for (int off = 32; off > 0; off >>= 1) {
    l0 = fmaxf(l0, __shfl_down(l0, off));
    l1 = fmaxf(l1, __shfl_down(l1, off));
  }
  int w = tid >> 6;
  if ((tid & 63) == 0) { red[0][w] = l0; red[1][w] = l1; }
  __syncthreads();
  float m0 = red[0][0], m1 = red[1][0];
#pragma unroll
  for (int q = 1; q < 6; ++q) { m0 = fmaxf(m0, red[0][q]); m1 = fmaxf(m1, red[1][q]); }
  float v0 = (a0 > 0.f) ? __expf(e0 - m0) : 0.f;
  float v1 = (a1 > 0.f) ? __expf(e1 - m1) : 0.f;
  float s0 = v0, s1 = v1;
#pragma unroll
  for (int off = 32; off > 0; off >>= 1) {
    s0 += __shfl_down(s0, off);
    s1 += __shfl_down(s1, off);
  }
  __syncthreads();
  if ((tid & 63) == 0) { red[0][w] = s0; red[1][w] = s1; }
  __syncthreads();
  float d0 = 0.f, d1 = 0.f;
#pragma unroll
  for (int q = 0; q < 6; ++q) { d0 += red[0][q]; d1 += red[1][q]; }
  float2 wv = make_float2(v0 * a0 / d0, v1 * a1 / d1);
  *(float2*)(att + (b * NN + tid) * NN + kk) = wv;   // row-major 8B store
}

// ================= k_out_hhA: 384 blocks x 256 thr, 2 rows/block ===========
__global__ __launch_bounds__(256) void k_out_hhA(
    const float* __restrict__ x, const float* __restrict__ hb,
    const float* __restrict__ att,
    const float* __restrict__ gW, const float* __restrict__ gb,
    const float* __restrict__ Wn, const float* __restrict__ Wbn,
    const float* __restrict__ An,
    float* __restrict__ xout,
    float* __restrict__ hbn, float* __restrict__ hAbn,
    float* __restrict__ hTqn, float* __restrict__ hATqn) {
  int r0 = blockIdx.x * 2;       // rows r0, r0+1 (same batch)
  int b = r0 / NN;
  int tid = threadIdx.x, c = tid & 127, jh = tid >> 7;
  __shared__ float ph[2][2][DD];   // [jh][row][c]
  __shared__ float redw[2][2];     // [row][wave-pair]
  float xr0 = x[(r0 + 0) * DD + c];   // prefetch
  float xr1 = x[(r0 + 1) * DD + c];
  float g1 = gW[c], g2 = gW[DD + c], gbv = gb[0];
  const float4* a0p = (const float4*)(att + (r0 + 0) * NN) + jh * 48;  // uniform
  const float4* a1p = (const float4*)(att + (r0 + 1) * NN) + jh * 48;
  const float* hp = hb + (b * NN + jh * 192) * DD + c;
  float q00 = 0.f, q01 = 0.f, q10 = 0.f, q11 = 0.f;
#pragma unroll 4
  for (int j4 = 0; j4 < 48; ++j4) {
    float4 av0 = a0p[j4], av1 = a1p[j4];
    const float* hj = hp + j4 * 4 * DD;
    float h0 = hj[0], h1v = hj[DD], h2v = hj[2 * DD], h3 = hj[3 * DD];
    q00 += av0.x * h0 + av0.y * h1v;
    q01 += av0.z * h2v + av0.w * h3;
    q10 += av1.x * h0 + av1.y * h1v;
    q11 += av1.z * h2v + av1.w * h3;
  }
  ph[jh][0][c] = q00 + q01;
  ph[jh][1][c] = q10 + q11;
  __syncthreads();
  float hpr0 = 0.f, hpr1 = 0.f;
  if (tid < 128) {
    hpr0 = fmaxf(ph[0][0][c] + ph[1][0][c], 0.f);
    hpr1 = fmaxf(ph[0][1][c] + ph[1][1][c], 0.f);
    float v0 = xr0 * g1 + hpr0 * g2;
    float v1 = xr1 * g1 + hpr1 * g2;
#pragma unroll
    for (int off = 32; off > 0; off >>= 1) {
      v0 += __shfl_down(v0, off);
      v1 += __shfl_down(v1, off);
    }
    if ((tid & 63) == 0) { redw[0][tid >> 6] = v0; redw[1][tid >> 6] = v1; }
  }
  __syncthreads();
  if (tid < 128) {
    float c0 = sigmoidf_(redw[0][0] + redw[0][1] + gbv);
    float c1 = sigmoidf_(redw[1][0] + redw[1][1] + gbv);
    xout[(r0 + 0) * DD + c] = c0 * xr0 + (1.f - c0) * hpr0;
    xout[(r0 + 1) * DD + c] = c1 * xr1 + (1.f - c1) * hpr1;
  }
  __syncthreads();
  // ---- h(l+1): W stream shared across 2 rows; k-half per jh
  const float* xb0 = xout + (r0 + 0) * DD + jh * 64;   // uniform
  const float* xb1 = xout + (r0 + 1) * DD + jh * 64;
  const float* Wp = Wn + (jh * 64) * DD + c;
  float a00 = 0.f, a01 = 0.f, a10 = 0.f, a11 = 0.f;
#pragma unroll 4
  for (int k = 0; k < 64; k += 2) {
    float w0 = Wp[k * DD], w1 = Wp[(k + 1) * DD];
    a00 += xb0[k] * w0; a01 += xb0[k + 1] * w1;
    a10 += xb1[k] * w0; a11 += xb1[k + 1] * w1;
  }
  ph[jh][0][c] = a00 + a01;
  ph[jh][1][c] = a10 + a11;
  __syncthreads();
  if (tid < 128) {
    float wb = Wbn[c];
    float hv0 = ph[0][0][c] + ph[1][0][c] + wb;
    float hv1 = ph[0][1][c] + ph[1][1][c] + wb;
    hbn[(r0 + 0) * DD + c] = hv0;
    hbn[(r0 + 1) * DD + c] = hv1;
    size_t gq = (size_t)((c >> 2) * 768) * 4 + (c & 3);
    hTqn[gq + (size_t)(r0 + 0) * 4] = hv0;
    hTqn[gq + (size_t)(r0 + 1) * 4] = hv1;
  }
  __syncthreads();
  // ---- hA(l+1): A stream shared across 2 rows
  const float* hb0p = hbn + (r0 + 0) * DD + jh * 64;   // uniform
  const float* hb1p = hbn + (r0 + 1) * DD + jh * 64;
  const float* Ap = An + (jh * 64) * DD + c;
  a00 = 0.f; a01 = 0.f; a10 = 0.f; a11 = 0.f;
#pragma unroll 4
  for (int k = 0; k < 64; k += 2) {
    float w0 = Ap[k * DD], w1 = Ap[(k + 1) * DD];
    a00 += hb0p[k] * w0; a01 += hb0p[k + 1] * w1;
    a10 += hb1p[k] * w0; a11 += hb1p[k + 1] * w1;
  }
  ph[jh][0][c] = a00 + a01;
  ph[jh][1][c] = a10 + a11;
  __syncthreads();
  if (tid < 128) {
    float av0 = ph[0][0][c] + ph[1][0][c];
    float av1 = ph[0][1][c] + ph[1][1][c];
    hAbn[(r0 + 0) * DD + c] = av0;
    hAbn[(r0 + 1) * DD + c] = av1;
    size_t gq = (size_t)((c >> 2) * 768) * 4 + (c & 3);
    hATqn[gq + (size_t)(r0 + 0) * 4] = av0;
    hATqn[gq + (size_t)(r0 + 1) * 4] = av1;
  }
}

// ================= k_out_proj: 768 blocks x 256 thr, 2 rows/block ==========
__global__ __launch_bounds__(256) void k_out_proj(
    const float* __restrict__ x, const float* __restrict__ hb,
    const float* __restrict__ att,
    const float* __restrict__ gW, const float* __restrict__ gb,
    const float* __restrict__ pW1, const float* __restrict__ pb1,
    const float* __restrict__ valid1, const float* __restrict__ h2g,
    float* __restrict__ xout, float* __restrict__ p1, float* __restrict__ p2q,
    float* __restrict__ wsi) {
  int blk = blockIdx.x, tid = threadIdx.x, c = tid & 127, jh = tid >> 7;
  if (blk >= 384) {
    // ---- protein projection, 2 rows per block
    int rp = (blk - 384) * 2;
    const float* xb0 = h2g + (rp + 0) * DD;   // uniform -> scalar path
    const float* xb1 = h2g + (rp + 1) * DD;
    for (int o = tid; o < 640; o += 256) {
      int m = o >> 7, hc = o & 127;
      const float* Wcol = pW1 + (m * 256 + 128) * HH + hc;
      float a00 = 0.f, a01 = 0.f, a10 = 0.f, a11 = 0.f;
#pragma unroll 4
      for (int k = 0; k < DD; k += 2) {
        float w0 = Wcol[k * HH], w1 = Wcol[(k + 1) * HH];
        a00 += xb0[k] * w0; a01 += xb0[k + 1] * w1;
        a10 += xb1[k] * w0; a11 += xb1[k + 1] * w1;
      }
      float* dst = p2q + (size_t)((m * 32 + (hc >> 2)) * 768 + rp) * 4 + (hc & 3);
      dst[0] = a00 + a01;
      dst[4] = a10 + a11;
    }
    return;
  }
  int r0 = blk * 2;
  int b = r0 / NN;
  __shared__ float ph[2][2][DD];
  __shared__ float redw[2][2];
  float xr0 = x[(r0 + 0) * DD + c];
  float xr1 = x[(r0 + 1) * DD + c];
  float g1 = gW[c], g2 = gW[DD + c], gbv = gb[0];
  float vld0 = valid1[r0], vld1 = valid1[r0 + 1];
  const float4* a0p = (const float4*)(att + (r0 + 0) * NN) + jh * 48;
  const float4* a1p = (const float4*)(att + (r0 + 1) * NN) + jh * 48;
  const float* hp = hb + (b * NN + jh * 192) * DD + c;
  float q00 = 0.f, q01 = 0.f, q10 = 0.f, q11 = 0.f;
#pragma unroll 4
  for (int j4 = 0; j4 < 48; ++j4) {
    float4 av0 = a0p[j4], av1 = a1p[j4];
    const float* hj = hp + j4 * 4 * DD;
    float h0 = hj[0], h1v = hj[DD], h2v = hj[2 * DD], h3 = hj[3 * DD];
    q00 += av0.x * h0 + av0.y * h1v;
    q01 += av0.z * h2v + av0.w * h3;
    q10 += av1.x * h0 + av1.y * h1v;
    q11 += av1.z * h2v + av1.w * h3;
  }
  ph[jh][0][c] = q00 + q01;
  ph[jh][1][c] = q10 + q11;
  __syncthreads();
  float hpr0 = 0.f, hpr1 = 0.f;
  if (tid < 128) {
    hpr0 = fmaxf(ph[0][0][c] + ph[1][0][c], 0.f);
    hpr1 = fmaxf(ph[0][1][c] + ph[1][1][c], 0.f);
    float v0 = xr0 * g1 + hpr0 * g2;
    float v1 = xr1 * g1 + hpr1 * g2;
#pragma unroll
    for (int off = 32; off > 0; off >>= 1) {
      v0 += __shfl_down(v0, off);
      v1 += __shfl_down(v1, off);
    }
    if ((tid & 63) == 0) { redw[0][tid >> 6] = v0; redw[1][tid >> 6] = v1; }
  }
  __syncthreads();
  if (tid < 128) {
    float c0 = sigmoidf_(redw[0][0] + redw[0][1] + gbv);
    float c1 = sigmoidf_(redw[1][0] + redw[1][1] + gbv);
    float nv0 = c0 * xr0 + (1.f - c0) * hpr0;
    float nv1 = c1 * xr1 + (1.f - c1) * hpr1;
    xout[(r0 + 0) * DD + c] = nv0;
    xout[(r0 + 1) * DD + c] = nv1;
    wsi[(r0 + 0) * DD + c] = nv0 * vld0;
    wsi[(r0 + 1) * DD + c] = nv1 * vld1;
  }
  __syncthreads();
  const float* xb0 = xout + (r0 + 0) * DD;   // uniform -> scalar path
  const float* xb1 = xout + (r0 + 1) * DD;
  for (int o = tid; o < 640; o += 256) {
    int m = o >> 7, hc = o & 127;
    const float* Wcol = pW1 + (m * 256) * HH + hc;
    float a00 = 0.f, a01 = 0.f, a10 = 0.f, a11 = 0.f;
#pragma unroll 4
    for (int k = 0; k < DD; k += 2) {
      float w0 = Wcol[k * HH], w1 = Wcol[(k + 1) * HH];
      a00 += xb0[k] * w0; a01 += xb0[k + 1] * w1;
      a10 += xb1[k] * w0; a11 += xb1[k + 1] * w1;
    }
    float bias = pb1[m * HH + hc];
    p1[((r0 + 0) * 5 + m) * HH + hc] = a00 + a01 + bias;
    p1[((r0 + 1) * 5 + m) * HH + hc] = a10 + a11 + bias;
  }
}

// ================= k_energy: 385 blocks x 384 thr ==========================
// hq-outer / m-inner: 5 independent p2q float4 streams in flight per batch.
__global__ __launch_bounds__(384) void k_energy(
    const float* __restrict__ p1, const float* __restrict__ p2q,
    const float* __restrict__ W2, const float* __restrict__ b2,
    const float* __restrict__ dmv, const float* __restrict__ charge1,
    const float* __restrict__ charge2, const float* __restrict__ veps,
    const float* __restrict__ vsig, const float* __restrict__ valid1,
    const float* __restrict__ valid2, const float* __restrict__ nm1,
    const float* __restrict__ nm2, const float* __restrict__ vdw_coeff,
    const float* __restrict__ wsi, const float* __restrict__ iW1,
    const float* __restrict__ ib1, const float* __restrict__ iW2,
    const float* __restrict__ ib2, float* __restrict__ out) {
  int blk = blockIdx.x, tid = threadIdx.x;
  if (blk >= 384) {   // ---- intercept finisher
    if (tid < 256) {
      int bb = tid >> 7, cc = tid & 127;
      __shared__ float hsf[2][DD];
      __shared__ float redf[2][2];
      float a0 = 0.f, a1 = 0.f;
      for (int q = 0; q < 384; q += 2) {
        a0 += wsi[(bb * 384 + q) * DD + cc];
        a1 += wsi[(bb * 384 + q + 1) * DD + cc];
      }
      hsf[bb][cc] = a0 + a1;
      __syncthreads();
      float hid = ib1[cc];
#pragma unroll 4
      for (int k = 0; k < DD; ++k) hid += hsf[bb][k] * iW1[k * HH + cc];
      hid = fmaxf(hid, 0.f);
      float v = hid * iW2[cc];
#pragma unroll
      for (int off = 32; off > 0; off >>= 1) v += __shfl_down(v, off);
      if ((tid & 63) == 0) redf[bb][(tid >> 6) & 1] = v;
      __syncthreads();
      if (tid < 2) out[tid * 4 + 3] = redf[tid][0] + redf[tid][1] + ib2[0];
    }
    return;
  }
  int r0 = blk * 2;
  int b = r0 / NN;
  int j = tid;
  int col = b * NN + j;
  // ---- prefetch HBM tail operands
  int p0 = r0 * NN + j, pI = p0 + NN;
  float dx0 = dmv[3 * p0], dy0 = dmv[3 * p0 + 1], dz0 = dmv[3 * p0 + 2];
  float dx1 = dmv[3 * pI], dy1 = dmv[3 * pI + 1], dz1 = dmv[3 * pI + 2];
  float ve0 = veps[p0], ve1 = veps[pI];
  float vs0 = vsig[p0], vs1 = vsig[pI];
  float q2c = charge2[col], vv2 = valid2[col], n2 = nm2[col];
  float c1a = charge1[r0], c1b = charge1[r0 + 1];
  float vaa = valid1[r0], vab = valid1[r0 + 1];
  float naa = nm1[r0], nab = nm1[r0 + 1];
  float vc2 = vdw_coeff[0] * vdw_coeff[0];

  const float* q0 = p1 + (r0 + 0) * 640;   // uniform -> s_load
  const float* q1 = p1 + (r0 + 1) * 640;
  const float4* pc = (const float4*)p2q + col;
  float acc0[5] = {0.f, 0.f, 0.f, 0.f, 0.f};
  float acc1[5] = {0.f, 0.f, 0.f, 0.f, 0.f};
#pragma unroll 2
  for (int hq = 0; hq < 32; ++hq) {
    float4 v[5];
#pragma unroll
    for (int m = 0; m < 5; ++m) v[m] = pc[(size_t)(m * 32 + hq) * 768];
#pragma unroll
    for (int m = 0; m < 5; ++m) {
      const float* x0m = q0 + m * HH + 4 * hq;
      const float* x1m = q1 + m * HH + 4 * hq;
      const float* w2m = W2 + m * HH + 4 * hq;
      float w0 = w2m[0], w1 = w2m[1], w2v = w2m[2], w3 = w2m[3];
      acc0[m] += fmaxf(x0m[0] + v[m].x, 0.f) * w0 + fmaxf(x0m[1] + v[m].y, 0.f) * w1
               + fmaxf(x0m[2] + v[m].z, 0.f) * w2v + fmaxf(x0m[3] + v[m].w, 0.f) * w3;
      acc1[m] += fmaxf(x1m[0] + v[m].x, 0.f) * w0 + fmaxf(x1m[1] + v[m].y, 0.f) * w1
               + fmaxf(x1m[2] + v[m].z, 0.f) * w2v + fmaxf(x1m[3] + v[m].w, 0.f) * w3;
    }
  }
#pragma unroll
  for (int m = 0; m < 5; ++m) { acc0[m] += b2[m]; acc1[m] += b2[m]; }

  float ec_sum = 0.f, ev_sum = 0.f;
  {
    float dm = sqrtf(dx0 * dx0 + dy0 * dy0 + dz0 * dz0 + 1e-10f);
    if (dm < 0.5f) dm = 1e10f;
    float cA = sigmoidf_(acc0[0]);
    float cN = sigmoidf_(acc0[1]) * 2.f + 1.f;
    float e_c = cA * c1a * q2c * __powf(1.f / dm, cN);
    e_c *= vaa * vv2;
    ec_sum += fminf(fmaxf(e_c, -100.f), 100.f);
    float vA = (sigmoidf_(acc0[2]) * 0.6f + 0.7f) * vc2 * ve0;
    float vB = tanhf_(acc0[3]) * 0.6f + 0.7f;
    float vN = sigmoidf_(acc0[4]) * 2.f + 5.f;
    float dm0 = vs0 * vB;
    if (dm0 < 1e-4f) dm0 = 1.f;
    float rr = __powf(dm0 / dm, vN);
    float e_v = vA * (rr * rr - 2.f * rr) * naa * n2;
    ev_sum += fminf(e_v, 100.f);
  }
  {
    float dm = sqrtf(dx1 * dx1 + dy1 * dy1 + dz1 * dz1 + 1e-10f);
    if (dm < 0.5f) dm = 1e10f;
    float cA = sigmoidf_(acc1[0]);
    float cN = sigmoidf_(acc1[1]) * 2.f + 1.f;
    float e_c = cA * c1b * q2c * __powf(1.f / dm, cN);
    e_c *= vab * vv2;
    ec_sum += fminf(fmaxf(e_c, -100.f), 100.f);
    float vA = (sigmoidf_(acc1[2]) * 0.6f + 0.7f) * vc2 * ve1;
    float vB = tanhf_(acc1[3]) * 0.6f + 0.7f;
    float vN = sigmoidf_(acc1[4]) * 2.f + 5.f;
    float dm0 = vs1 * vB;
    if (dm0 < 1e-4f) dm0 = 1.f;
    float rr = __powf(dm0 / dm, vN);
    float e_v = vA * (rr * rr - 2.f * rr) * nab * n2;
    ev_sum += fminf(e_v, 100.f);
  }
#pragma unroll
  for (int off = 32; off > 0; off >>= 1) {
    ec_sum += __shfl_down(ec_sum, off);
    ev_sum += __shfl_down(ev_sum, off);
  }
  __shared__ float rec[6], rev[6];
  if ((tid & 63) == 0) { rec[tid >> 6] = ec_sum; rev[tid >> 6] = ev_sum; }
  __syncthreads();
  if (tid == 0) {
    float a = 0.f, c = 0.f;
#pragma unroll
    for (int w = 0; w < 6; ++w) { a += rec[w]; c += rev[w]; }
    atomicAdd(&out[b * 4 + 0], a);
    atomicAdd(&out[b * 4 + 1], c);
  }
}

// ---------------------------------------------------------------- launch
extern "C" void kernel_launch(void* const* d_in, const int* in_sizes, int n_in,
                              void* d_out, int out_size, void* d_ws, size_t ws_size,
                              hipStream_t stream) {
  (void)in_sizes; (void)n_in; (void)out_size; (void)ws_size;
  const float* h1         = (const float*)d_in[0];
  const float* h2         = (const float*)d_in[1];
  const float* adj1       = (const float*)d_in[2];
  const float* dmv        = (const float*)d_in[3];
  const float* charge1    = (const float*)d_in[4];
  const float* charge2    = (const float*)d_in[5];
  const float* veps       = (const float*)d_in[6];
  const float* vsig       = (const float*)d_in[7];
  const float* delta_uff  = (const float*)d_in[8];
  const float* valid1     = (const float*)d_in[9];
  const float* valid2     = (const float*)d_in[10];
  const float* nm1        = (const float*)d_in[11];
  const float* nm2        = (const float*)d_in[12];
  const float* node_W     = (const float*)d_in[13];
  const float* gat_W      = (const float*)d_in[14];
  const float* gat_Wb     = (const float*)d_in[15];
  const float* gat_A      = (const float*)d_in[16];
  const float* gat_gW     = (const float*)d_in[17];
  const float* gat_gb     = (const float*)d_in[18];
  const float* pW1        = (const float*)d_in[19];
  const float* pb1        = (const float*)d_in[20];
  const float* pW2        = (const float*)d_in[21];
  const float* pb2        = (const float*)d_in[22];
  const float* vdw_coeff  = (const float*)d_in[23];
  const float* duff_coeff = (const float*)d_in[24];
  const float* iW1        = (const float*)d_in[25];
  const float* ib1        = (const float*)d_in[26];
  const float* iW2        = (const float*)d_in[27];
  const float* ib2        = (const float*)d_in[28];
  float* out = (float*)d_out;

  float* ws = (float*)d_ws;
  const int RN = 768 * DD;  // 98304
  float* h1gA  = ws;               // x ping-pong A
  float* h1gB  = h1gA + RN;        // x ping-pong B
  float* h2g   = h1gB + RN;
  float* hb0   = h2g  + RN;
  float* hA0   = hb0  + RN;
  float* hTq0  = hA0  + RN;
  float* hATq0 = hTq0 + RN;
  float* hb1   = hATq0 + RN;
  float* hA1   = hb1  + RN;
  float* hTq1  = hA1  + RN;
  float* hATq1 = hTq1 + RN;
  float* att   = hATq1 + RN;           // 2*384*384
  float* p1    = att + 2 * NN * NN;    // 768*640
  float* p2q   = p1 + 768 * 640;       // 768*640 packed
  float* wsi   = p2q + 768 * 640;      // 768*128

  const int DD2 = DD * DD;

  k_start<<<dim3(768), dim3(256), 0, stream>>>(
      h1, h2, node_W, gat_W, gat_Wb, gat_A, delta_uff, duff_coeff,
      h1gA, h2g, hb0, hA0, hTq0, hATq0, out);

  // layer 0
  k_att<<<dim3(384), dim3(384), 0, stream>>>(hb0, hA0, hTq0, hATq0, adj1, att);
  k_out_hhA<<<dim3(384), dim3(256), 0, stream>>>(
      h1gA, hb0, att, gat_gW + 0, gat_gb + 0,
      gat_W + DD2, gat_Wb + DD, gat_A + DD2,
      h1gB, hb1, hA1, hTq1, hATq1);
  // layer 1
  k_att<<<dim3(384), dim3(384), 0, stream>>>(hb1, hA1, hTq1, hATq1, adj1, att);
  k_out_hhA<<<dim3(384), dim3(256), 0, stream>>>(
      h1gB, hb1, att, gat_gW + 2 * DD, gat_gb + 1,
      gat_W + 2 * DD2, gat_Wb + 2 * DD, gat_A + 2 * DD2,
      h1gA, hb0, hA0, hTq0, hATq0);
  // layer 2
  k_att<<<dim3(384), dim3(384), 0, stream>>>(hb0, hA0, hTq0, hATq0, adj1, att);
  k_out_proj<<<dim3(768), dim3(256), 0, stream>>>(
      h1gA, hb0, att, gat_gW + 4 * DD, gat_gb + 2,
      pW1, pb1, valid1, h2g, h1gB, p1, p2q, wsi);

  k_energy<<<dim3(385), dim3(384), 0, stream>>>(
      p1, p2q, pW2, pb2, dmv, charge1, charge2, veps, vsig,
      valid1, valid2, nm1, nm2, vdw_coeff, wsi, iW1, ib1, iW2, ib2, out);
}